// Round 1
// baseline (983.407 us; speedup 1.0000x reference)
//
#include <hip/hip_runtime.h>
#include <hip/hip_bf16.h>

#define DD 128

// ---------------- edge dtype detect + normalize ----------------
__global__ void k_detect(const int* __restrict__ e, int pairs, int* __restrict__ flag) {
  __shared__ int nz;
  if (threadIdx.x == 0) nz = 0;
  __syncthreads();
  int samples = pairs < 4096 ? pairs : 4096;
  for (int i = threadIdx.x; i < samples; i += blockDim.x)
    if (e[2 * i + 1] != 0) atomicAdd(&nz, 1);
  __syncthreads();
  if (threadIdx.x == 0) *flag = (nz == 0) ? 1 : 0;  // 1 => underlying int64
}

__global__ void k_convert(const void* __restrict__ eptr, int E, const int* __restrict__ flag,
                          int* __restrict__ s32, int* __restrict__ d32) {
  int i = blockIdx.x * 256 + threadIdx.x;
  if (i >= E) return;
  if (*flag) {
    const long long* p = (const long long*)eptr;
    s32[i] = (int)p[i];
    d32[i] = (int)p[E + i];
  } else {
    const int* p = (const int*)eptr;
    s32[i] = p[i];
    d32[i] = p[E + i];
  }
}

// ---------------- degree / dinv ----------------
__global__ void k_count(const int* __restrict__ d32, int E, int* __restrict__ degi) {
  int i = blockIdx.x * 256 + threadIdx.x;
  if (i < E) atomicAdd(&degi[d32[i]], 1);
}

__global__ void k_dinv(const int* __restrict__ degi, float* __restrict__ dinv, int n) {
  int i = blockIdx.x * 256 + threadIdx.x;
  if (i < n) dinv[i] = rsqrtf((float)degi[i] + 1.0f);
}

// ---------------- single-block exclusive scan (row_ptr) ----------------
__global__ void k_scan(const int* __restrict__ cnt, int* __restrict__ rp, int n) {
  __shared__ int wsum[16];
  __shared__ int ctot;
  int t = threadIdx.x, lane = t & 63, wid = t >> 6;
  int base = 0;
  for (int start = 0; start < n; start += 1024) {
    int i = start + t;
    int v = (i < n) ? cnt[i] : 0;
    int incl = v;
#pragma unroll
    for (int o = 1; o < 64; o <<= 1) {
      int u = __shfl_up(incl, o);
      if (lane >= o) incl += u;
    }
    if (lane == 63) wsum[wid] = incl;
    __syncthreads();
    if (t < 16) {
      int s = wsum[t];
      int e = s;
#pragma unroll
      for (int o = 1; o < 16; o <<= 1) {
        int u = __shfl_up(e, o, 16);
        if (t >= o) e += u;
      }
      wsum[t] = e - s;  // exclusive wave offset
      if (t == 15) ctot = e;
    }
    __syncthreads();
    if (i < n) rp[i] = base + wsum[wid] + incl - v;
    base += ctot;
    __syncthreads();
  }
  if (t == 0) rp[n] = base;
}

__global__ void k_scatter(const int* __restrict__ s32, const int* __restrict__ d32,
                          const int* __restrict__ rp, int* __restrict__ cur,
                          int* __restrict__ csrc, int E) {
  int i = blockIdx.x * 256 + threadIdx.x;
  if (i < E) {
    int d = d32[i];
    int pos = rp[d] + atomicAdd(&cur[d], 1);
    csrc[pos] = s32[i];
  }
}

// ---------------- GEMM: H = (A @ W) * dinv[row]  (A: n x 128, W: 128 x 128) ----------------
__global__ __launch_bounds__(256) void k_gemm(const float* __restrict__ A,
                                              const float* __restrict__ W,
                                              const float* __restrict__ dinv,
                                              float* __restrict__ H, int n) {
  __shared__ float Wl[64 * DD];
  int t = threadIdx.x;
  int rg = t >> 3;           // 0..31 -> 2 rows each
  int cg = (t & 7) * 16;     // 16-col group
  int r0 = blockIdx.x * 64 + rg * 2;
  int r1 = r0 + 1;
  bool ok0 = r0 < n, ok1 = r1 < n;
  float acc0[16], acc1[16];
#pragma unroll
  for (int j = 0; j < 16; ++j) { acc0[j] = 0.f; acc1[j] = 0.f; }
  const float* A0 = A + (size_t)r0 * DD;
  const float* A1 = A + (size_t)r1 * DD;
  for (int kc = 0; kc < 2; ++kc) {
    __syncthreads();
#pragma unroll
    for (int i = t; i < 64 * DD / 4; i += 256)
      ((float4*)Wl)[i] = ((const float4*)(W + kc * 64 * DD))[i];
    __syncthreads();
    for (int k = 0; k < 64; k += 4) {
      float4 a0 = ok0 ? *(const float4*)(A0 + kc * 64 + k) : make_float4(0, 0, 0, 0);
      float4 a1 = ok1 ? *(const float4*)(A1 + kc * 64 + k) : make_float4(0, 0, 0, 0);
      float av0[4] = {a0.x, a0.y, a0.z, a0.w};
      float av1[4] = {a1.x, a1.y, a1.z, a1.w};
#pragma unroll
      for (int kk = 0; kk < 4; ++kk) {
        const float* wr = Wl + (k + kk) * DD + cg;
#pragma unroll
        for (int j = 0; j < 16; ++j) {
          acc0[j] = fmaf(av0[kk], wr[j], acc0[j]);
          acc1[j] = fmaf(av1[kk], wr[j], acc1[j]);
        }
      }
    }
  }
  if (ok0) {
    float s = dinv[r0];
    float4* o = (float4*)(H + (size_t)r0 * DD + cg);
#pragma unroll
    for (int q = 0; q < 4; ++q)
      o[q] = make_float4(acc0[q * 4] * s, acc0[q * 4 + 1] * s, acc0[q * 4 + 2] * s, acc0[q * 4 + 3] * s);
  }
  if (ok1) {
    float s = dinv[r1];
    float4* o = (float4*)(H + (size_t)r1 * DD + cg);
#pragma unroll
    for (int q = 0; q < 4; ++q)
      o[q] = make_float4(acc1[q * 4] * s, acc1[q * 4 + 1] * s, acc1[q * 4 + 2] * s, acc1[q * 4 + 3] * s);
  }
}

// ---------------- aggregation: y = relu(dinv[v]*(hs[v] + sum_{u in N(v)} hs[u]) + b) ----------------
__global__ __launch_bounds__(256) void k_agg(const float* __restrict__ hs,
                                             const float* __restrict__ dinv,
                                             const float* __restrict__ b,
                                             const int* __restrict__ rp,
                                             const int* __restrict__ csrc,
                                             float* __restrict__ y, int n) {
  int wid = threadIdx.x >> 6, lane = threadIdx.x & 63;
  int v = blockIdx.x * 4 + wid;
  if (v >= n) return;
  int e0 = rp[v], e1 = rp[v + 1];
  const float2* H2 = (const float2*)hs;
  float ax = 0.f, ay = 0.f;
  for (int eb = e0; eb < e1; eb += 64) {
    int ecnt = e1 - eb;
    if (ecnt > 64) ecnt = 64;
    int ul = (eb + lane < e1) ? csrc[eb + lane] : 0;
    for (int tt = 0; tt < ecnt; ++tt) {
      int u = __shfl(ul, tt);
      float2 hv = H2[(size_t)u * 64 + lane];
      ax += hv.x;
      ay += hv.y;
    }
  }
  float2 hv = H2[(size_t)v * 64 + lane];
  float dv = dinv[v];
  float2 bb = ((const float2*)b)[lane];
  float ox = fmaf(dv, ax + hv.x, bb.x);
  float oy = fmaf(dv, ay + hv.y, bb.y);
  ((float2*)y)[(size_t)v * 64 + lane] = make_float2(fmaxf(ox, 0.f), fmaxf(oy, 0.f));
}

// ---------------- BN stats over virtual concat [x|y1|y2] ----------------
__global__ void k_bnstats(const float* __restrict__ x, const float* __restrict__ y1,
                          const float* __restrict__ y2, float* __restrict__ colsum,
                          float* __restrict__ colsq, int n, int rpb) {
  int c = threadIdx.x;  // 0..383
  const float* buf = (c < 128) ? x : (c < 256) ? y1 : y2;
  int cc = c & 127;
  int r0 = blockIdx.x * rpb;
  int r1 = r0 + rpb;
  if (r1 > n) r1 = n;
  float s = 0.f, q = 0.f;
  for (int r = r0; r < r1; ++r) {
    float vv = buf[(size_t)r * DD + cc];
    s += vv;
    q = fmaf(vv, vv, q);
  }
  atomicAdd(&colsum[c], s);
  atomicAdd(&colsq[c], q);
}

// ---------------- fold BN into Wo', bo' ----------------
__global__ void k_fold(const float* __restrict__ colsum, const float* __restrict__ colsq,
                       const float* __restrict__ gamma, const float* __restrict__ beta,
                       const float* __restrict__ Wo, const float* __restrict__ bo,
                       float* __restrict__ WoP, float* __restrict__ boP, int n) {
  __shared__ float aS[384], cS[384];
  int t = threadIdx.x;  // 0..383
  float inv_n = 1.0f / (float)n;
  float mu = colsum[t] * inv_n;
  float var = colsq[t] * inv_n - mu * mu;
  float a = gamma[t] * rsqrtf(var + 1e-5f);
  aS[t] = a;
  cS[t] = beta[t] - mu * a;
  __syncthreads();
  for (int i = t; i < 384 * DD; i += 384)
    WoP[i] = aS[i >> 7] * Wo[i];
  if (t < DD) {
    float s = bo[t];
    for (int k = 0; k < 384; ++k)
      s = fmaf(cS[k], Wo[k * DD + t], s);
    boP[t] = s;
  }
}

// ---------------- final GEMM: out = [x|y1|y2] @ WoP + boP ----------------
__global__ __launch_bounds__(256) void k_gemm_out(const float* __restrict__ x,
                                                  const float* __restrict__ y1,
                                                  const float* __restrict__ y2,
                                                  const float* __restrict__ WoP,
                                                  const float* __restrict__ boP,
                                                  float* __restrict__ out, int n) {
  __shared__ float Wl[64 * DD];
  int t = threadIdx.x;
  int rg = t >> 3;
  int cg = (t & 7) * 16;
  int r0 = blockIdx.x * 64 + rg * 2;
  int r1 = r0 + 1;
  bool ok0 = r0 < n, ok1 = r1 < n;
  float acc0[16], acc1[16];
#pragma unroll
  for (int j = 0; j < 16; ++j) { acc0[j] = 0.f; acc1[j] = 0.f; }
  for (int p = 0; p < 3; ++p) {
    const float* A = (p == 0) ? x : (p == 1) ? y1 : y2;
    const float* A0 = A + (size_t)r0 * DD;
    const float* A1 = A + (size_t)r1 * DD;
    for (int kc = 0; kc < 2; ++kc) {
      __syncthreads();
#pragma unroll
      for (int i = t; i < 64 * DD / 4; i += 256)
        ((float4*)Wl)[i] = ((const float4*)(WoP + p * DD * DD + kc * 64 * DD))[i];
      __syncthreads();
      for (int k = 0; k < 64; k += 4) {
        float4 a0 = ok0 ? *(const float4*)(A0 + kc * 64 + k) : make_float4(0, 0, 0, 0);
        float4 a1 = ok1 ? *(const float4*)(A1 + kc * 64 + k) : make_float4(0, 0, 0, 0);
        float av0[4] = {a0.x, a0.y, a0.z, a0.w};
        float av1[4] = {a1.x, a1.y, a1.z, a1.w};
#pragma unroll
        for (int kk = 0; kk < 4; ++kk) {
          const float* wr = Wl + (k + kk) * DD + cg;
#pragma unroll
          for (int j = 0; j < 16; ++j) {
            acc0[j] = fmaf(av0[kk], wr[j], acc0[j]);
            acc1[j] = fmaf(av1[kk], wr[j], acc1[j]);
          }
        }
      }
    }
  }
  if (ok0) {
    float* o = out + (size_t)r0 * DD + cg;
#pragma unroll
    for (int j = 0; j < 16; ++j) o[j] = acc0[j] + boP[cg + j];
  }
  if (ok1) {
    float* o = out + (size_t)r1 * DD + cg;
#pragma unroll
    for (int j = 0; j < 16; ++j) o[j] = acc1[j] + boP[cg + j];
  }
}

extern "C" void kernel_launch(void* const* d_in, const int* in_sizes, int n_in,
                              void* d_out, int out_size, void* d_ws, size_t ws_size,
                              hipStream_t stream) {
  const float* x = (const float*)d_in[0];
  const void* ept = d_in[1];
  const float* W1 = (const float*)d_in[2];
  const float* b1 = (const float*)d_in[3];
  const float* W2 = (const float*)d_in[4];
  const float* b2 = (const float*)d_in[5];
  const float* gamma = (const float*)d_in[6];
  const float* beta = (const float*)d_in[7];
  const float* Wo = (const float*)d_in[8];
  const float* bo = (const float*)d_in[9];
  float* out = (float*)d_out;
  int N = in_sizes[0] / DD;
  int E = in_sizes[1] / 2;

  char* w = (char*)d_ws;
  size_t off = 0;
  auto alloc = [&](size_t bytes) {
    void* p = w + off;
    off = (off + bytes + 255) & ~(size_t)255;
    return p;
  };
  float* dinv = (float*)alloc((size_t)N * 4);
  int* degi = (int*)alloc((size_t)N * 4);
  int* rp = (int*)alloc((size_t)(N + 1) * 4);
  int* csrc = (int*)alloc((size_t)E * 4);
  int* s32 = (int*)alloc((size_t)E * 4);
  int* d32 = (int*)alloc((size_t)E * 4);
  float* h = (float*)alloc((size_t)N * DD * 4);
  float* y1 = (float*)alloc((size_t)N * DD * 4);
  float* y2 = (float*)alloc((size_t)N * DD * 4);
  float* colsum = (float*)alloc(384 * 4);
  float* colsq = (float*)alloc(384 * 4);
  float* WoP = (float*)alloc(384 * DD * 4);
  float* boP = (float*)alloc(DD * 4);
  int* flag = (int*)alloc(4);

  hipMemsetAsync(degi, 0, (size_t)N * 4, stream);
  hipMemsetAsync(colsum, 0, 384 * 4, stream);
  hipMemsetAsync(colsq, 0, 384 * 4, stream);

  int eb = (E + 255) / 256;
  int nb = (N + 255) / 256;
  k_detect<<<1, 256, 0, stream>>>((const int*)ept, E, flag);
  k_convert<<<eb, 256, 0, stream>>>(ept, E, flag, s32, d32);
  k_count<<<eb, 256, 0, stream>>>(d32, E, degi);
  k_dinv<<<nb, 256, 0, stream>>>(degi, dinv, N);
  k_scan<<<1, 1024, 0, stream>>>(degi, rp, N);
  hipMemsetAsync(degi, 0, (size_t)N * 4, stream);  // reuse as scatter cursor
  k_scatter<<<eb, 256, 0, stream>>>(s32, d32, rp, degi, csrc, E);

  int gb = (N + 63) / 64;
  int ab = (N + 3) / 4;
  k_gemm<<<gb, 256, 0, stream>>>(x, W1, dinv, h, N);
  k_agg<<<ab, 256, 0, stream>>>(h, dinv, b1, rp, csrc, y1, N);
  k_gemm<<<gb, 256, 0, stream>>>(y1, W2, dinv, h, N);
  k_agg<<<ab, 256, 0, stream>>>(h, dinv, b2, rp, csrc, y2, N);

  k_bnstats<<<nb, 384, 0, stream>>>(x, y1, y2, colsum, colsq, N, 256);
  k_fold<<<1, 384, 0, stream>>>(colsum, colsq, gamma, beta, Wo, bo, WoP, boP, N);
  k_gemm_out<<<gb, 256, 0, stream>>>(x, y1, y2, WoP, boP, out, N);
}

// Round 2
// 712.592 us; speedup vs baseline: 1.3800x; 1.3800x over previous
//
#include <hip/hip_runtime.h>
#include <hip/hip_bf16.h>

#define DD 128
typedef __attribute__((ext_vector_type(8))) short bf16x8;
typedef __attribute__((ext_vector_type(4))) float f32x4;
typedef unsigned int uint32;
typedef unsigned short ushort16;

__device__ __forceinline__ unsigned short f2b(float f) {
  __hip_bfloat16 h = __float2bfloat16(f);
  unsigned short u;
  __builtin_memcpy(&u, &h, 2);
  return u;
}
__device__ __forceinline__ float b2f_lo(uint32 v) { return __uint_as_float(v << 16); }
__device__ __forceinline__ float b2f_hi(uint32 v) { return __uint_as_float(v & 0xffff0000u); }

// ---------------- edge dtype detect + normalize ----------------
__global__ void k_detect(const int* __restrict__ e, int pairs, int* __restrict__ flag) {
  __shared__ int nz;
  if (threadIdx.x == 0) nz = 0;
  __syncthreads();
  int samples = pairs < 4096 ? pairs : 4096;
  for (int i = threadIdx.x; i < samples; i += blockDim.x)
    if (e[2 * i + 1] != 0) atomicAdd(&nz, 1);
  __syncthreads();
  if (threadIdx.x == 0) *flag = (nz == 0) ? 1 : 0;  // 1 => underlying int64
}

__global__ void k_convert(const void* __restrict__ eptr, int E, const int* __restrict__ flag,
                          int* __restrict__ s32, int* __restrict__ d32) {
  int i = blockIdx.x * 256 + threadIdx.x;
  if (i >= E) return;
  if (*flag) {
    const long long* p = (const long long*)eptr;
    s32[i] = (int)p[i];
    d32[i] = (int)p[E + i];
  } else {
    const int* p = (const int*)eptr;
    s32[i] = p[i];
    d32[i] = p[E + i];
  }
}

// ---------------- degree / dinv ----------------
__global__ void k_count(const int* __restrict__ d32, int E, int* __restrict__ degi) {
  int i = blockIdx.x * 256 + threadIdx.x;
  if (i < E) atomicAdd(&degi[d32[i]], 1);
}

__global__ void k_dinv(const int* __restrict__ degi, float* __restrict__ dinv, int n) {
  int i = blockIdx.x * 256 + threadIdx.x;
  if (i < n) dinv[i] = rsqrtf((float)degi[i] + 1.0f);
}

// ---------------- single-block exclusive scan (row_ptr) ----------------
__global__ void k_scan(const int* __restrict__ cnt, int* __restrict__ rp, int n) {
  __shared__ int wsum[16];
  __shared__ int ctot;
  int t = threadIdx.x, lane = t & 63, wid = t >> 6;
  int base = 0;
  for (int start = 0; start < n; start += 1024) {
    int i = start + t;
    int v = (i < n) ? cnt[i] : 0;
    int incl = v;
#pragma unroll
    for (int o = 1; o < 64; o <<= 1) {
      int u = __shfl_up(incl, o);
      if (lane >= o) incl += u;
    }
    if (lane == 63) wsum[wid] = incl;
    __syncthreads();
    if (t < 16) {
      int s = wsum[t];
      int e = s;
#pragma unroll
      for (int o = 1; o < 16; o <<= 1) {
        int u = __shfl_up(e, o, 16);
        if (t >= o) e += u;
      }
      wsum[t] = e - s;
      if (t == 15) ctot = e;
    }
    __syncthreads();
    if (i < n) rp[i] = base + wsum[wid] + incl - v;
    base += ctot;
    __syncthreads();
  }
  if (t == 0) rp[n] = base;
}

__global__ void k_scatter(const int* __restrict__ s32, const int* __restrict__ d32,
                          const int* __restrict__ rp, int* __restrict__ cur,
                          int* __restrict__ csrc, int E) {
  int i = blockIdx.x * 256 + threadIdx.x;
  if (i < E) {
    int d = d32[i];
    int pos = rp[d] + atomicAdd(&cur[d], 1);
    csrc[pos] = s32[i];
  }
}

// ---------------- x -> bf16 ----------------
__global__ void k_cvt_x(const float4* __restrict__ x, ushort4* __restrict__ xb, int n4) {
  int i = blockIdx.x * 256 + threadIdx.x;
  if (i >= n4) return;
  float4 a = x[i];
  ushort4 o;
  o.x = f2b(a.x); o.y = f2b(a.y); o.z = f2b(a.z); o.w = f2b(a.w);
  xb[i] = o;
}

// ---------------- W1/W2 -> pre-swizzled bf16 LDS image [col][k-chunk^swz] ----------------
__global__ void k_prep_w(const float* __restrict__ W1, const float* __restrict__ W2,
                         unsigned short* __restrict__ wimg) {
  int i = blockIdx.x * 256 + threadIdx.x;  // 0..32767
  if (i >= 32768) return;
  int wsel = i >> 14;
  int j = i & 16383;
  int k = j >> 7, col = j & 127;
  float v = (wsel ? W2 : W1)[j];
  int chunk = (k >> 3) ^ (col & 7);
  wimg[wsel * 16384 + col * 128 + chunk * 8 + (k & 7)] = f2b(v);
}

// ---------------- MFMA GEMM: H = bf16((A @ W) * dinv[row])  ----------------
__global__ __launch_bounds__(256) void k_gemm(const unsigned short* __restrict__ Ab,
                                              const unsigned short* __restrict__ Wimg,
                                              const float* __restrict__ dinv,
                                              unsigned short* __restrict__ H, int n) {
  __shared__ __align__(16) unsigned short Wl[16384];
  int t = threadIdx.x, lane = t & 63, w = t >> 6;
#pragma unroll
  for (int i = t; i < 2048; i += 256) ((int4*)Wl)[i] = ((const int4*)Wimg)[i];
  __syncthreads();
  int rowBase = blockIdx.x * 128 + w * 32;
  int r16 = lane & 15, half = lane >> 4;
  f32x4 acc[2][8];
#pragma unroll
  for (int m = 0; m < 2; ++m)
#pragma unroll
    for (int nn = 0; nn < 8; ++nn) acc[m][nn] = (f32x4){0.f, 0.f, 0.f, 0.f};
#pragma unroll
  for (int ks = 0; ks < 4; ++ks) {
    bf16x8 a[2];
#pragma unroll
    for (int m = 0; m < 2; ++m) {
      int r = rowBase + m * 16 + r16;
      if (r >= n) r = n - 1;
      a[m] = *(const bf16x8*)(Ab + (size_t)r * DD + ks * 32 + half * 8);
    }
#pragma unroll
    for (int nn = 0; nn < 8; ++nn) {
      int col = nn * 16 + r16;
      int chunk = (ks * 4 + half) ^ (col & 7);
      bf16x8 b = *(const bf16x8*)(Wl + col * 128 + chunk * 8);
      acc[0][nn] = __builtin_amdgcn_mfma_f32_16x16x32_bf16(a[0], b, acc[0][nn], 0, 0, 0);
      acc[1][nn] = __builtin_amdgcn_mfma_f32_16x16x32_bf16(a[1], b, acc[1][nn], 0, 0, 0);
    }
  }
#pragma unroll
  for (int m = 0; m < 2; ++m) {
    int rb = rowBase + m * 16 + half * 4;
    float dv[4];
#pragma unroll
    for (int i = 0; i < 4; ++i) dv[i] = (rb + i < n) ? dinv[rb + i] : 0.f;
#pragma unroll
    for (int nn = 0; nn < 8; ++nn) {
      int col = nn * 16 + r16;
#pragma unroll
      for (int i = 0; i < 4; ++i) {
        int r = rb + i;
        if (r < n) H[(size_t)r * DD + col] = f2b(acc[m][nn][i] * dv[i]);
      }
    }
  }
}

// ---------------- aggregation (bf16 gather) ----------------
__global__ __launch_bounds__(256) void k_agg(const unsigned short* __restrict__ hs,
                                             const float* __restrict__ dinv,
                                             const float* __restrict__ b,
                                             const int* __restrict__ rp,
                                             const int* __restrict__ csrc,
                                             unsigned short* __restrict__ y, int n) {
  int wid = threadIdx.x >> 6, lane = threadIdx.x & 63;
  int v = blockIdx.x * 4 + wid;
  if (v >= n) return;
  int e0 = rp[v], e1 = rp[v + 1];
  const uint32* H = (const uint32*)hs;
  float ax = 0.f, ay = 0.f;
  for (int eb = e0; eb < e1; eb += 64) {
    int ec = e1 - eb;
    if (ec > 64) ec = 64;
    int ul = (eb + lane < e1) ? csrc[eb + lane] : 0;
    for (int tt = 0; tt < ec; ++tt) {
      int u = __shfl(ul, tt);
      uint32 hv = H[(size_t)u * 64 + lane];
      ax += b2f_lo(hv);
      ay += b2f_hi(hv);
    }
  }
  uint32 hv = H[(size_t)v * 64 + lane];
  float dv = dinv[v];
  float2 bb = ((const float2*)b)[lane];
  float ox = fmaf(dv, ax + b2f_lo(hv), bb.x);
  float oy = fmaf(dv, ay + b2f_hi(hv), bb.y);
  ox = fmaxf(ox, 0.f);
  oy = fmaxf(oy, 0.f);
  uint32 o = (uint32)f2b(ox) | ((uint32)f2b(oy) << 16);
  ((uint32*)y)[(size_t)v * 64 + lane] = o;
}

// ---------------- BN stats (bf16 inputs) ----------------
__global__ void k_bnstats(const unsigned short* __restrict__ xb, const unsigned short* __restrict__ y1,
                          const unsigned short* __restrict__ y2, float* __restrict__ colsum,
                          float* __restrict__ colsq, int n, int rpb) {
  int t = threadIdx.x;  // 0..191
  const unsigned short* buf = (t < 64) ? xb : (t < 128) ? y1 : y2;
  int uc = t & 63;
  int r0 = blockIdx.x * rpb;
  int r1 = r0 + rpb;
  if (r1 > n) r1 = n;
  float s0 = 0.f, s1 = 0.f, q0 = 0.f, q1 = 0.f;
  const uint32* B = (const uint32*)buf;
  for (int r = r0; r < r1; ++r) {
    uint32 v = B[(size_t)r * 64 + uc];
    float a = b2f_lo(v), c = b2f_hi(v);
    s0 += a; s1 += c;
    q0 = fmaf(a, a, q0);
    q1 = fmaf(c, c, q1);
  }
  int c0 = (t >> 6) * 128 + uc * 2;
  atomicAdd(&colsum[c0], s0);
  atomicAdd(&colsum[c0 + 1], s1);
  atomicAdd(&colsq[c0], q0);
  atomicAdd(&colsq[c0 + 1], q1);
}

// ---------------- BN fold: scale/shift + folded bias ----------------
__global__ void k_fold_a(const float* __restrict__ colsum, const float* __restrict__ colsq,
                         const float* __restrict__ gamma, const float* __restrict__ beta,
                         const float* __restrict__ Wo, const float* __restrict__ bo,
                         float* __restrict__ aS, float* __restrict__ cS, float* __restrict__ boP,
                         int n) {
  __shared__ float cSh[384];
  int t = threadIdx.x;  // 0..383
  float inv_n = 1.0f / (float)n;
  float mu = colsum[t] * inv_n;
  float var = colsq[t] * inv_n - mu * mu;
  float a = gamma[t] * rsqrtf(var + 1e-5f);
  aS[t] = a;
  float c = beta[t] - mu * a;
  cS[t] = c;
  cSh[t] = c;
  __syncthreads();
  if (t < DD) {
    float s = bo[t];
    for (int k = 0; k < 384; ++k) s = fmaf(cSh[k], Wo[k * DD + t], s);
    boP[t] = s;
  }
}

// ---------------- WoP image (bf16, pre-swizzled) ----------------
__global__ void k_foldw(const float* __restrict__ aS, const float* __restrict__ Wo,
                        unsigned short* __restrict__ wopimg) {
  int i = blockIdx.x * 256 + threadIdx.x;  // 0..49151
  if (i >= 49152) return;
  int krow = i >> 7, col = i & 127;
  float v = aS[krow] * Wo[i];
  int p = krow >> 7, kk = krow & 127;
  int chunk = (kk >> 3) ^ (col & 7);
  wopimg[p * 16384 + col * 128 + chunk * 8 + (kk & 7)] = f2b(v);
}

// ---------------- final MFMA GEMM: out = [xb|y1|y2] @ WoP + boP (f32 out) ----------------
__global__ __launch_bounds__(256) void k_gemm_out(const unsigned short* __restrict__ xb,
                                                  const unsigned short* __restrict__ y1,
                                                  const unsigned short* __restrict__ y2,
                                                  const unsigned short* __restrict__ Wimg3,
                                                  const float* __restrict__ boP,
                                                  float* __restrict__ out, int n) {
  __shared__ __align__(16) unsigned short Wl[16384];
  int t = threadIdx.x, lane = t & 63, w = t >> 6;
  int rowBase = blockIdx.x * 128 + w * 32;
  int r16 = lane & 15, half = lane >> 4;
  f32x4 acc[2][8];
#pragma unroll
  for (int m = 0; m < 2; ++m)
#pragma unroll
    for (int nn = 0; nn < 8; ++nn) acc[m][nn] = (f32x4){0.f, 0.f, 0.f, 0.f};
  for (int p = 0; p < 3; ++p) {
    const unsigned short* Ab = (p == 0) ? xb : (p == 1) ? y1 : y2;
    __syncthreads();
#pragma unroll
    for (int i = t; i < 2048; i += 256) ((int4*)Wl)[i] = ((const int4*)(Wimg3 + p * 16384))[i];
    __syncthreads();
#pragma unroll
    for (int ks = 0; ks < 4; ++ks) {
      bf16x8 a[2];
#pragma unroll
      for (int m = 0; m < 2; ++m) {
        int r = rowBase + m * 16 + r16;
        if (r >= n) r = n - 1;
        a[m] = *(const bf16x8*)(Ab + (size_t)r * DD + ks * 32 + half * 8);
      }
#pragma unroll
      for (int nn = 0; nn < 8; ++nn) {
        int col = nn * 16 + r16;
        int chunk = (ks * 4 + half) ^ (col & 7);
        bf16x8 b = *(const bf16x8*)(Wl + col * 128 + chunk * 8);
        acc[0][nn] = __builtin_amdgcn_mfma_f32_16x16x32_bf16(a[0], b, acc[0][nn], 0, 0, 0);
        acc[1][nn] = __builtin_amdgcn_mfma_f32_16x16x32_bf16(a[1], b, acc[1][nn], 0, 0, 0);
      }
    }
  }
#pragma unroll
  for (int m = 0; m < 2; ++m) {
    int rb = rowBase + m * 16 + half * 4;
#pragma unroll
    for (int nn = 0; nn < 8; ++nn) {
      int col = nn * 16 + r16;
      float bb = boP[col];
#pragma unroll
      for (int i = 0; i < 4; ++i) {
        int r = rb + i;
        if (r < n) out[(size_t)r * DD + col] = acc[m][nn][i] + bb;
      }
    }
  }
}

extern "C" void kernel_launch(void* const* d_in, const int* in_sizes, int n_in,
                              void* d_out, int out_size, void* d_ws, size_t ws_size,
                              hipStream_t stream) {
  const float* x = (const float*)d_in[0];
  const void* ept = d_in[1];
  const float* W1 = (const float*)d_in[2];
  const float* b1 = (const float*)d_in[3];
  const float* W2 = (const float*)d_in[4];
  const float* b2 = (const float*)d_in[5];
  const float* gamma = (const float*)d_in[6];
  const float* beta = (const float*)d_in[7];
  const float* Wo = (const float*)d_in[8];
  const float* bo = (const float*)d_in[9];
  float* out = (float*)d_out;
  int N = in_sizes[0] / DD;
  int E = in_sizes[1] / 2;

  char* w = (char*)d_ws;
  size_t off = 0;
  auto alloc = [&](size_t bytes) {
    void* p = w + off;
    off = (off + bytes + 255) & ~(size_t)255;
    return p;
  };
  float* dinv = (float*)alloc((size_t)N * 4);
  int* degi = (int*)alloc((size_t)N * 4);
  int* rp = (int*)alloc((size_t)(N + 1) * 4);
  int* csrc = (int*)alloc((size_t)E * 4);
  int* s32 = (int*)alloc((size_t)E * 4);
  int* d32 = (int*)alloc((size_t)E * 4);
  unsigned short* xb = (unsigned short*)alloc((size_t)N * DD * 2);
  unsigned short* h = (unsigned short*)alloc((size_t)N * DD * 2);
  unsigned short* y1 = (unsigned short*)alloc((size_t)N * DD * 2);
  unsigned short* y2 = (unsigned short*)alloc((size_t)N * DD * 2);
  unsigned short* wimg = (unsigned short*)alloc(32768 * 2);
  unsigned short* wopimg = (unsigned short*)alloc(49152 * 2);
  float* colsum = (float*)alloc(384 * 4);
  float* colsq = (float*)alloc(384 * 4);
  float* aS = (float*)alloc(384 * 4);
  float* cS = (float*)alloc(384 * 4);
  float* boP = (float*)alloc(DD * 4);
  int* flag = (int*)alloc(4);

  hipMemsetAsync(degi, 0, (size_t)N * 4, stream);
  hipMemsetAsync(colsum, 0, 384 * 4, stream);
  hipMemsetAsync(colsq, 0, 384 * 4, stream);

  int eb = (E + 255) / 256;
  int nb = (N + 255) / 256;
  k_detect<<<1, 256, 0, stream>>>((const int*)ept, E, flag);
  k_convert<<<eb, 256, 0, stream>>>(ept, E, flag, s32, d32);
  k_count<<<eb, 256, 0, stream>>>(d32, E, degi);
  k_dinv<<<nb, 256, 0, stream>>>(degi, dinv, N);
  k_scan<<<1, 1024, 0, stream>>>(degi, rp, N);
  hipMemsetAsync(degi, 0, (size_t)N * 4, stream);  // reuse as scatter cursor
  k_scatter<<<eb, 256, 0, stream>>>(s32, d32, rp, degi, csrc, E);

  int n4 = N * DD / 4;
  k_cvt_x<<<(n4 + 255) / 256, 256, 0, stream>>>((const float4*)x, (ushort4*)xb, n4);
  k_prep_w<<<128, 256, 0, stream>>>(W1, W2, wimg);

  int gb = (N + 127) / 128;
  int ab = (N + 3) / 4;
  k_gemm<<<gb, 256, 0, stream>>>(xb, wimg, dinv, h, N);
  k_agg<<<ab, 256, 0, stream>>>(h, dinv, b1, rp, csrc, y1, N);
  k_gemm<<<gb, 256, 0, stream>>>(y1, wimg + 16384, dinv, h, N);
  k_agg<<<ab, 256, 0, stream>>>(h, dinv, b2, rp, csrc, y2, N);

  k_bnstats<<<(N + 511) / 512, 192, 0, stream>>>(xb, y1, y2, colsum, colsq, N, 512);
  k_fold_a<<<1, 384, 0, stream>>>(colsum, colsq, gamma, beta, Wo, bo, aS, cS, boP, N);
  k_foldw<<<192, 256, 0, stream>>>(aS, Wo, wopimg);
  k_gemm_out<<<gb, 256, 0, stream>>>(xb, y1, y2, wopimg, boP, out, N);
}

// Round 3
// 643.979 us; speedup vs baseline: 1.5271x; 1.1065x over previous
//
#include <hip/hip_runtime.h>
#include <hip/hip_bf16.h>

#define DD 128
typedef __attribute__((ext_vector_type(8))) short bf16x8;
typedef __attribute__((ext_vector_type(4))) float f32x4;
typedef unsigned int uint32;

__device__ __forceinline__ unsigned short f2b(float f) {
  __hip_bfloat16 h = __float2bfloat16(f);
  unsigned short u;
  __builtin_memcpy(&u, &h, 2);
  return u;
}
__device__ __forceinline__ float b2f_lo(uint32 v) { return __uint_as_float(v << 16); }
__device__ __forceinline__ float b2f_hi(uint32 v) { return __uint_as_float(v & 0xffff0000u); }

// ---------------- edge dtype detect + normalize ----------------
__global__ void k_detect(const int* __restrict__ e, int pairs, int* __restrict__ flag) {
  __shared__ int nz;
  if (threadIdx.x == 0) nz = 0;
  __syncthreads();
  int samples = pairs < 4096 ? pairs : 4096;
  for (int i = threadIdx.x; i < samples; i += blockDim.x)
    if (e[2 * i + 1] != 0) atomicAdd(&nz, 1);
  __syncthreads();
  if (threadIdx.x == 0) *flag = (nz == 0) ? 1 : 0;  // 1 => underlying int64
}

__global__ void k_convert(const void* __restrict__ eptr, int E, const int* __restrict__ flag,
                          int* __restrict__ s32, int* __restrict__ d32) {
  int i = blockIdx.x * 256 + threadIdx.x;
  if (i >= E) return;
  if (*flag) {
    const long long* p = (const long long*)eptr;
    s32[i] = (int)p[i];
    d32[i] = (int)p[E + i];
  } else {
    const int* p = (const int*)eptr;
    s32[i] = p[i];
    d32[i] = p[E + i];
  }
}

// ---------------- degree / dinv ----------------
__global__ void k_count(const int* __restrict__ d32, int E, int* __restrict__ degi) {
  int i = blockIdx.x * 256 + threadIdx.x;
  if (i < E) atomicAdd(&degi[d32[i]], 1);
}

__global__ void k_dinv(const int* __restrict__ degi, float* __restrict__ dinv, int n) {
  int i = blockIdx.x * 256 + threadIdx.x;
  if (i < n) dinv[i] = rsqrtf((float)degi[i] + 1.0f);
}

// ---------------- 3-phase parallel exclusive scan ----------------
// phase 1: per-block (256 elems) exclusive scan + block sums
__global__ void k_scan1(const int* __restrict__ cnt, int* __restrict__ rp,
                        int* __restrict__ bsum, int n) {
  __shared__ int ws[4];
  int t = threadIdx.x, lane = t & 63, wv = t >> 6;
  int i = blockIdx.x * 256 + t;
  int v = (i < n) ? cnt[i] : 0;
  int incl = v;
#pragma unroll
  for (int o = 1; o < 64; o <<= 1) {
    int u = __shfl_up(incl, o);
    if (lane >= o) incl += u;
  }
  if (lane == 63) ws[wv] = incl;
  __syncthreads();
  int off = 0;
  for (int k = 0; k < wv; ++k) off += ws[k];
  if (i < n) rp[i] = incl - v + off;
  if (t == 255) bsum[blockIdx.x] = off + incl;
}

// phase 2: single-block exclusive scan of block sums (small)
__global__ void k_scan2(const int* __restrict__ cnt, int* __restrict__ rp, int n) {
  __shared__ int wsum[16];
  __shared__ int ctot;
  int t = threadIdx.x, lane = t & 63, wid = t >> 6;
  int base = 0;
  for (int start = 0; start < n; start += 1024) {
    int i = start + t;
    int v = (i < n) ? cnt[i] : 0;
    int incl = v;
#pragma unroll
    for (int o = 1; o < 64; o <<= 1) {
      int u = __shfl_up(incl, o);
      if (lane >= o) incl += u;
    }
    if (lane == 63) wsum[wid] = incl;
    __syncthreads();
    if (t < 16) {
      int s = wsum[t];
      int e = s;
#pragma unroll
      for (int o = 1; o < 16; o <<= 1) {
        int u = __shfl_up(e, o, 16);
        if (t >= o) e += u;
      }
      wsum[t] = e - s;
      if (t == 15) ctot = e;
    }
    __syncthreads();
    if (i < n) rp[i] = base + wsum[wid] + incl - v;
    base += ctot;
    __syncthreads();
  }
  if (t == 0) rp[n] = base;
}

// phase 3: add block offsets
__global__ void k_scan3(int* __restrict__ rp, const int* __restrict__ bsumex, int n, int nb) {
  int i = blockIdx.x * 256 + threadIdx.x;
  if (i < n) rp[i] += bsumex[blockIdx.x];
  if (i == 0) rp[n] = bsumex[nb];
}

__global__ void k_scatter(const int* __restrict__ s32, const int* __restrict__ d32,
                          const int* __restrict__ rp, int* __restrict__ cur,
                          int* __restrict__ csrc, int E) {
  int i = blockIdx.x * 256 + threadIdx.x;
  if (i < E) {
    int d = d32[i];
    int pos = rp[d] + atomicAdd(&cur[d], 1);
    csrc[pos] = s32[i];
  }
}

// ---------------- x -> bf16 ----------------
__global__ void k_cvt_x(const float4* __restrict__ x, ushort4* __restrict__ xb, int n4) {
  int i = blockIdx.x * 256 + threadIdx.x;
  if (i >= n4) return;
  float4 a = x[i];
  ushort4 o;
  o.x = f2b(a.x); o.y = f2b(a.y); o.z = f2b(a.z); o.w = f2b(a.w);
  xb[i] = o;
}

// ---------------- W1/W2 -> pre-swizzled bf16 LDS image [col][k-chunk^swz] ----------------
__global__ void k_prep_w(const float* __restrict__ W1, const float* __restrict__ W2,
                         unsigned short* __restrict__ wimg) {
  int i = blockIdx.x * 256 + threadIdx.x;  // 0..32767
  if (i >= 32768) return;
  int wsel = i >> 14;
  int j = i & 16383;
  int k = j >> 7, col = j & 127;
  float v = (wsel ? W2 : W1)[j];
  int chunk = (k >> 3) ^ (col & 7);
  wimg[wsel * 16384 + col * 128 + chunk * 8 + (k & 7)] = f2b(v);
}

// ---------------- MFMA GEMM: H = bf16((A @ W) * dinv[row])  ----------------
__global__ __launch_bounds__(256) void k_gemm(const unsigned short* __restrict__ Ab,
                                              const unsigned short* __restrict__ Wimg,
                                              const float* __restrict__ dinv,
                                              unsigned short* __restrict__ H, int n) {
  __shared__ __align__(16) unsigned short Wl[16384];
  int t = threadIdx.x, lane = t & 63, w = t >> 6;
#pragma unroll
  for (int i = t; i < 2048; i += 256) ((int4*)Wl)[i] = ((const int4*)Wimg)[i];
  __syncthreads();
  int rowBase = blockIdx.x * 128 + w * 32;
  int r16 = lane & 15, half = lane >> 4;
  f32x4 acc[2][8];
#pragma unroll
  for (int m = 0; m < 2; ++m)
#pragma unroll
    for (int nn = 0; nn < 8; ++nn) acc[m][nn] = (f32x4){0.f, 0.f, 0.f, 0.f};
#pragma unroll
  for (int ks = 0; ks < 4; ++ks) {
    bf16x8 a[2];
#pragma unroll
    for (int m = 0; m < 2; ++m) {
      int r = rowBase + m * 16 + r16;
      if (r >= n) r = n - 1;
      a[m] = *(const bf16x8*)(Ab + (size_t)r * DD + ks * 32 + half * 8);
    }
#pragma unroll
    for (int nn = 0; nn < 8; ++nn) {
      int col = nn * 16 + r16;
      int chunk = (ks * 4 + half) ^ (col & 7);
      bf16x8 b = *(const bf16x8*)(Wl + col * 128 + chunk * 8);
      acc[0][nn] = __builtin_amdgcn_mfma_f32_16x16x32_bf16(a[0], b, acc[0][nn], 0, 0, 0);
      acc[1][nn] = __builtin_amdgcn_mfma_f32_16x16x32_bf16(a[1], b, acc[1][nn], 0, 0, 0);
    }
  }
#pragma unroll
  for (int m = 0; m < 2; ++m) {
    int rb = rowBase + m * 16 + half * 4;
    float dv[4];
#pragma unroll
    for (int i = 0; i < 4; ++i) dv[i] = (rb + i < n) ? dinv[rb + i] : 0.f;
#pragma unroll
    for (int nn = 0; nn < 8; ++nn) {
      int col = nn * 16 + r16;
#pragma unroll
      for (int i = 0; i < 4; ++i) {
        int r = rb + i;
        if (r < n) H[(size_t)r * DD + col] = f2b(acc[m][nn][i] * dv[i]);
      }
    }
  }
}

// ---------------- aggregation (bf16 gather) ----------------
__global__ __launch_bounds__(256) void k_agg(const unsigned short* __restrict__ hs,
                                             const float* __restrict__ dinv,
                                             const float* __restrict__ b,
                                             const int* __restrict__ rp,
                                             const int* __restrict__ csrc,
                                             unsigned short* __restrict__ y, int n) {
  int wid = threadIdx.x >> 6, lane = threadIdx.x & 63;
  int v = blockIdx.x * 4 + wid;
  if (v >= n) return;
  int e0 = rp[v], e1 = rp[v + 1];
  const uint32* H = (const uint32*)hs;
  float ax = 0.f, ay = 0.f;
  for (int eb = e0; eb < e1; eb += 64) {
    int ec = e1 - eb;
    if (ec > 64) ec = 64;
    int ul = (eb + lane < e1) ? csrc[eb + lane] : 0;
    for (int tt = 0; tt < ec; ++tt) {
      int u = __shfl(ul, tt);
      uint32 hv = H[(size_t)u * 64 + lane];
      ax += b2f_lo(hv);
      ay += b2f_hi(hv);
    }
  }
  uint32 hv = H[(size_t)v * 64 + lane];
  float dv = dinv[v];
  float2 bb = ((const float2*)b)[lane];
  float ox = fmaf(dv, ax + b2f_lo(hv), bb.x);
  float oy = fmaf(dv, ay + b2f_hi(hv), bb.y);
  ox = fmaxf(ox, 0.f);
  oy = fmaxf(oy, 0.f);
  uint32 o = (uint32)f2b(ox) | ((uint32)f2b(oy) << 16);
  ((uint32*)y)[(size_t)v * 64 + lane] = o;
}

// ---------------- BN stats (bf16 inputs, high occupancy) ----------------
__global__ __launch_bounds__(256) void k_bnstats(const uint32* __restrict__ xb,
                                                 const uint32* __restrict__ y1,
                                                 const uint32* __restrict__ y2,
                                                 float* __restrict__ colsum,
                                                 float* __restrict__ colsq,
                                                 int n, int bpb) {
  int buf = blockIdx.x / bpb;
  int bid = blockIdx.x % bpb;
  const uint32* B = (buf == 0) ? xb : (buf == 1) ? y1 : y2;
  int t = threadIdx.x, uc = t & 63, rr = t >> 2 >> 4;  // rr = t>>6
  rr = t >> 6;
  float s0 = 0.f, s1 = 0.f, q0 = 0.f, q1 = 0.f;
  for (int r = bid * 4 + rr; r < n; r += bpb * 4) {
    uint32 v = B[(size_t)r * 64 + uc];
    float a = b2f_lo(v), c = b2f_hi(v);
    s0 += a; s1 += c;
    q0 = fmaf(a, a, q0);
    q1 = fmaf(c, c, q1);
  }
  __shared__ float sh0[256], sh1[256], sh2[256], sh3[256];
  sh0[t] = s0; sh1[t] = s1; sh2[t] = q0; sh3[t] = q1;
  __syncthreads();
  if (rr == 0) {
#pragma unroll
    for (int k = 1; k < 4; ++k) {
      s0 += sh0[k * 64 + uc];
      s1 += sh1[k * 64 + uc];
      q0 += sh2[k * 64 + uc];
      q1 += sh3[k * 64 + uc];
    }
    int c0 = buf * 128 + uc * 2;
    atomicAdd(&colsum[c0], s0);
    atomicAdd(&colsum[c0 + 1], s1);
    atomicAdd(&colsq[c0], q0);
    atomicAdd(&colsq[c0 + 1], q1);
  }
}

// ---------------- BN fold: scale/shift + folded bias ----------------
__global__ void k_fold_a(const float* __restrict__ colsum, const float* __restrict__ colsq,
                         const float* __restrict__ gamma, const float* __restrict__ beta,
                         const float* __restrict__ Wo, const float* __restrict__ bo,
                         float* __restrict__ aS, float* __restrict__ cS, float* __restrict__ boP,
                         int n) {
  __shared__ float cSh[384];
  int t = threadIdx.x;  // 0..383
  float inv_n = 1.0f / (float)n;
  float mu = colsum[t] * inv_n;
  float var = colsq[t] * inv_n - mu * mu;
  float a = gamma[t] * rsqrtf(var + 1e-5f);
  aS[t] = a;
  float c = beta[t] - mu * a;
  cS[t] = c;
  cSh[t] = c;
  __syncthreads();
  if (t < DD) {
    float s = bo[t];
    for (int k = 0; k < 384; ++k) s = fmaf(cSh[k], Wo[k * DD + t], s);
    boP[t] = s;
  }
}

// ---------------- WoP image (bf16, pre-swizzled) ----------------
__global__ void k_foldw(const float* __restrict__ aS, const float* __restrict__ Wo,
                        unsigned short* __restrict__ wopimg) {
  int i = blockIdx.x * 256 + threadIdx.x;  // 0..49151
  if (i >= 49152) return;
  int krow = i >> 7, col = i & 127;
  float v = aS[krow] * Wo[i];
  int p = krow >> 7, kk = krow & 127;
  int chunk = (kk >> 3) ^ (col & 7);
  wopimg[p * 16384 + col * 128 + chunk * 8 + (kk & 7)] = f2b(v);
}

// ---------------- final MFMA GEMM: out = [xb|y1|y2] @ WoP + boP (f32 out) ----------------
__global__ __launch_bounds__(256) void k_gemm_out(const unsigned short* __restrict__ xb,
                                                  const unsigned short* __restrict__ y1,
                                                  const unsigned short* __restrict__ y2,
                                                  const unsigned short* __restrict__ Wimg3,
                                                  const float* __restrict__ boP,
                                                  float* __restrict__ out, int n) {
  __shared__ __align__(16) unsigned short Wl[16384];
  int t = threadIdx.x, lane = t & 63, w = t >> 6;
  int rowBase = blockIdx.x * 128 + w * 32;
  int r16 = lane & 15, half = lane >> 4;
  f32x4 acc[2][8];
#pragma unroll
  for (int m = 0; m < 2; ++m)
#pragma unroll
    for (int nn = 0; nn < 8; ++nn) acc[m][nn] = (f32x4){0.f, 0.f, 0.f, 0.f};
  for (int p = 0; p < 3; ++p) {
    const unsigned short* Ab = (p == 0) ? xb : (p == 1) ? y1 : y2;
    __syncthreads();
#pragma unroll
    for (int i = t; i < 2048; i += 256) ((int4*)Wl)[i] = ((const int4*)(Wimg3 + p * 16384))[i];
    __syncthreads();
#pragma unroll
    for (int ks = 0; ks < 4; ++ks) {
      bf16x8 a[2];
#pragma unroll
      for (int m = 0; m < 2; ++m) {
        int r = rowBase + m * 16 + r16;
        if (r >= n) r = n - 1;
        a[m] = *(const bf16x8*)(Ab + (size_t)r * DD + ks * 32 + half * 8);
      }
#pragma unroll
      for (int nn = 0; nn < 8; ++nn) {
        int col = nn * 16 + r16;
        int chunk = (ks * 4 + half) ^ (col & 7);
        bf16x8 b = *(const bf16x8*)(Wl + col * 128 + chunk * 8);
        acc[0][nn] = __builtin_amdgcn_mfma_f32_16x16x32_bf16(a[0], b, acc[0][nn], 0, 0, 0);
        acc[1][nn] = __builtin_amdgcn_mfma_f32_16x16x32_bf16(a[1], b, acc[1][nn], 0, 0, 0);
      }
    }
  }
#pragma unroll
  for (int m = 0; m < 2; ++m) {
    int rb = rowBase + m * 16 + half * 4;
#pragma unroll
    for (int nn = 0; nn < 8; ++nn) {
      int col = nn * 16 + r16;
      float bb = boP[col];
#pragma unroll
      for (int i = 0; i < 4; ++i) {
        int r = rb + i;
        if (r < n) out[(size_t)r * DD + col] = acc[m][nn][i] + bb;
      }
    }
  }
}

extern "C" void kernel_launch(void* const* d_in, const int* in_sizes, int n_in,
                              void* d_out, int out_size, void* d_ws, size_t ws_size,
                              hipStream_t stream) {
  const float* x = (const float*)d_in[0];
  const void* ept = d_in[1];
  const float* W1 = (const float*)d_in[2];
  const float* b1 = (const float*)d_in[3];
  const float* W2 = (const float*)d_in[4];
  const float* b2 = (const float*)d_in[5];
  const float* gamma = (const float*)d_in[6];
  const float* beta = (const float*)d_in[7];
  const float* Wo = (const float*)d_in[8];
  const float* bo = (const float*)d_in[9];
  float* out = (float*)d_out;
  int N = in_sizes[0] / DD;
  int E = in_sizes[1] / 2;

  char* w = (char*)d_ws;
  size_t off = 0;
  auto alloc = [&](size_t bytes) {
    void* p = w + off;
    off = (off + bytes + 255) & ~(size_t)255;
    return p;
  };
  float* dinv = (float*)alloc((size_t)N * 4);
  int* degi = (int*)alloc((size_t)N * 4);
  int* rp = (int*)alloc((size_t)(N + 1) * 4);
  int* csrc = (int*)alloc((size_t)E * 4);
  int* s32 = (int*)alloc((size_t)E * 4);
  int* d32 = (int*)alloc((size_t)E * 4);
  unsigned short* xb = (unsigned short*)alloc((size_t)N * DD * 2);
  unsigned short* h = (unsigned short*)alloc((size_t)N * DD * 2);
  unsigned short* y1 = (unsigned short*)alloc((size_t)N * DD * 2);
  unsigned short* y2 = (unsigned short*)alloc((size_t)N * DD * 2);
  unsigned short* wimg = (unsigned short*)alloc(32768 * 2);
  unsigned short* wopimg = (unsigned short*)alloc(49152 * 2);
  float* colsum = (float*)alloc(384 * 4);
  float* colsq = (float*)alloc(384 * 4);
  float* aS = (float*)alloc(384 * 4);
  float* cS = (float*)alloc(384 * 4);
  float* boP = (float*)alloc(DD * 4);
  int* flag = (int*)alloc(4);
  int nbs = (N + 255) / 256;  // scan blocks
  int* bsum = (int*)alloc((size_t)(nbs + 1) * 4);

  hipMemsetAsync(degi, 0, (size_t)N * 4, stream);
  hipMemsetAsync(colsum, 0, 384 * 4, stream);
  hipMemsetAsync(colsq, 0, 384 * 4, stream);

  int eb = (E + 255) / 256;
  int nb = (N + 255) / 256;
  k_detect<<<1, 256, 0, stream>>>((const int*)ept, E, flag);
  k_convert<<<eb, 256, 0, stream>>>(ept, E, flag, s32, d32);
  k_count<<<eb, 256, 0, stream>>>(d32, E, degi);
  k_dinv<<<nb, 256, 0, stream>>>(degi, dinv, N);
  k_scan1<<<nbs, 256, 0, stream>>>(degi, rp, bsum, N);
  k_scan2<<<1, 1024, 0, stream>>>(bsum, bsum, nbs);  // in-place exclusive scan of block sums
  k_scan3<<<nbs, 256, 0, stream>>>(rp, bsum, N, nbs);
  hipMemsetAsync(degi, 0, (size_t)N * 4, stream);  // reuse as scatter cursor
  k_scatter<<<eb, 256, 0, stream>>>(s32, d32, rp, degi, csrc, E);

  int n4 = N * DD / 4;
  k_cvt_x<<<(n4 + 255) / 256, 256, 0, stream>>>((const float4*)x, (ushort4*)xb, n4);
  k_prep_w<<<128, 256, 0, stream>>>(W1, W2, wimg);

  int gb = (N + 127) / 128;
  int ab = (N + 3) / 4;
  k_gemm<<<gb, 256, 0, stream>>>(xb, wimg, dinv, h, N);
  k_agg<<<ab, 256, 0, stream>>>(h, dinv, b1, rp, csrc, y1, N);
  k_gemm<<<gb, 256, 0, stream>>>(y1, wimg + 16384, dinv, h, N);
  k_agg<<<ab, 256, 0, stream>>>(h, dinv, b2, rp, csrc, y2, N);

  int bpb = 1024;
  k_bnstats<<<3 * bpb, 256, 0, stream>>>((const uint32*)xb, (const uint32*)y1,
                                         (const uint32*)y2, colsum, colsq, N, bpb);
  k_fold_a<<<1, 384, 0, stream>>>(colsum, colsq, gamma, beta, Wo, bo, aS, cS, boP, N);
  k_foldw<<<192, 256, 0, stream>>>(aS, Wo, wopimg);
  k_gemm_out<<<gb, 256, 0, stream>>>(xb, y1, y2, wopimg, boP, out, N);
}

// Round 4
// 602.839 us; speedup vs baseline: 1.6313x; 1.0682x over previous
//
#include <hip/hip_runtime.h>
#include <hip/hip_bf16.h>

#define DD 128
#define NBLK 256     // blocks for hist/place passes
#define MAXBUK 1024  // max dst-buckets (256 nodes each) supported by LDS path
#define CAP2 12288   // max edges per bucket for LDS sort staging

typedef __attribute__((ext_vector_type(8))) short bf16x8;
typedef __attribute__((ext_vector_type(4))) float f32x4;
typedef unsigned int uint32;

__device__ __forceinline__ unsigned short f2b(float f) {
  __hip_bfloat16 h = __float2bfloat16(f);
  unsigned short u;
  __builtin_memcpy(&u, &h, 2);
  return u;
}
__device__ __forceinline__ float b2f_lo(uint32 v) { return __uint_as_float(v << 16); }
__device__ __forceinline__ float b2f_hi(uint32 v) { return __uint_as_float(v & 0xffff0000u); }

// ---------------- edge dtype detect ----------------
__global__ void k_detect(const int* __restrict__ e, int pairs, int* __restrict__ flag) {
  __shared__ int nz;
  if (threadIdx.x == 0) nz = 0;
  __syncthreads();
  int samples = pairs < 4096 ? pairs : 4096;
  for (int i = threadIdx.x; i < samples; i += blockDim.x)
    if (e[2 * i + 1] != 0) atomicAdd(&nz, 1);
  __syncthreads();
  if (threadIdx.x == 0) *flag = (nz == 0) ? 1 : 0;  // 1 => underlying int64
}

// ---------------- degree count + per-block bucket histogram ----------------
__global__ __launch_bounds__(256) void k_hist(const void* __restrict__ eptr, int E,
                                              const int* __restrict__ flag,
                                              int* __restrict__ degi, int* __restrict__ histT,
                                              int nbuk, int dohist) {
  __shared__ int hist[MAXBUK];
  int t = threadIdx.x, blk = blockIdx.x;
  if (dohist)
    for (int b = t; b < nbuk; b += 256) hist[b] = 0;
  __syncthreads();
  int chunk = (E + NBLK - 1) / NBLK;
  int i0 = blk * chunk, i1 = min(E, i0 + chunk);
  bool f = (*flag) != 0;
  for (int i = i0 + t; i < i1; i += 256) {
    int dst = f ? (int)((const long long*)eptr)[E + i] : ((const int*)eptr)[E + i];
    atomicAdd(&degi[dst], 1);
    if (dohist) atomicAdd(&hist[dst >> 8], 1);
  }
  __syncthreads();
  if (dohist)
    for (int b = t; b < nbuk; b += 256) histT[b * NBLK + blk] = hist[b];
}

__global__ void k_dinv(const int* __restrict__ degi, float* __restrict__ dinv, int n) {
  int i = blockIdx.x * 256 + threadIdx.x;
  if (i < n) dinv[i] = rsqrtf((float)degi[i] + 1.0f);
}

// ---------------- 3-phase parallel exclusive scan (rp over degi) ----------------
__global__ void k_scan1(const int* __restrict__ cnt, int* __restrict__ rp,
                        int* __restrict__ bsum, int n) {
  __shared__ int ws[4];
  int t = threadIdx.x, lane = t & 63, wv = t >> 6;
  int i = blockIdx.x * 256 + t;
  int v = (i < n) ? cnt[i] : 0;
  int incl = v;
#pragma unroll
  for (int o = 1; o < 64; o <<= 1) {
    int u = __shfl_up(incl, o);
    if (lane >= o) incl += u;
  }
  if (lane == 63) ws[wv] = incl;
  __syncthreads();
  int off = 0;
  for (int k = 0; k < wv; ++k) off += ws[k];
  if (i < n) rp[i] = incl - v + off;
  if (t == 255) bsum[blockIdx.x] = off + incl;
}

__global__ void k_scan2(const int* __restrict__ cnt, int* __restrict__ rp, int n) {
  __shared__ int wsum[16];
  __shared__ int ctot;
  int t = threadIdx.x, lane = t & 63, wid = t >> 6;
  int base = 0;
  for (int start = 0; start < n; start += 1024) {
    int i = start + t;
    int v = (i < n) ? cnt[i] : 0;
    int incl = v;
#pragma unroll
    for (int o = 1; o < 64; o <<= 1) {
      int u = __shfl_up(incl, o);
      if (lane >= o) incl += u;
    }
    if (lane == 63) wsum[wid] = incl;
    __syncthreads();
    if (t < 16) {
      int s = wsum[t];
      int e = s;
#pragma unroll
      for (int o = 1; o < 16; o <<= 1) {
        int u = __shfl_up(e, o, 16);
        if (t >= o) e += u;
      }
      wsum[t] = e - s;
      if (t == 15) ctot = e;
    }
    __syncthreads();
    if (i < n) rp[i] = base + wsum[wid] + incl - v;
    base += ctot;
    __syncthreads();
  }
  if (t == 0) rp[n] = base;
}

__global__ void k_scan3(int* __restrict__ rp, const int* __restrict__ bsumex, int n, int nb) {
  int i = blockIdx.x * 256 + threadIdx.x;
  if (i < n) rp[i] += bsumex[blockIdx.x];
  if (i == 0) rp[n] = bsumex[nb];
}

// ---------------- bucket scan: offs[b][blk] = global write base ----------------
__global__ void k_bscan(const int* __restrict__ histT, const int* __restrict__ rp,
                        int* __restrict__ offs, int nbuk) {
  int t = threadIdx.x, lane = t & 63, wid = t >> 6;
  int b = blockIdx.x * 4 + wid;
  if (b >= nbuk) return;
  int base = rp[b << 8];
  int idx = b * NBLK + lane * 4;
  int v0 = histT[idx], v1 = histT[idx + 1], v2 = histT[idx + 2], v3 = histT[idx + 3];
  int lsum = v0 + v1 + v2 + v3;
  int incl = lsum;
#pragma unroll
  for (int o = 1; o < 64; o <<= 1) {
    int u = __shfl_up(incl, o);
    if (lane >= o) incl += u;
  }
  int excl = base + incl - lsum;
  offs[idx] = excl;
  offs[idx + 1] = excl + v0;
  offs[idx + 2] = excl + v0 + v1;
  offs[idx + 3] = excl + v0 + v1 + v2;
}

// ---------------- place edges into bucket regions (block-contiguous runs) ----------------
__global__ __launch_bounds__(256) void k_place(const void* __restrict__ eptr, int E,
                                               const int* __restrict__ flag,
                                               const int* __restrict__ offs,
                                               int* __restrict__ ebuk, int nbuk) {
  __shared__ int cur[MAXBUK];
  int t = threadIdx.x, blk = blockIdx.x;
  for (int b = t; b < nbuk; b += 256) cur[b] = offs[b * NBLK + blk];
  __syncthreads();
  int chunk = (E + NBLK - 1) / NBLK;
  int i0 = blk * chunk, i1 = min(E, i0 + chunk);
  bool f = (*flag) != 0;
  for (int i = i0 + t; i < i1; i += 256) {
    int src, dst;
    if (f) {
      src = (int)((const long long*)eptr)[i];
      dst = (int)((const long long*)eptr)[E + i];
    } else {
      src = ((const int*)eptr)[i];
      dst = ((const int*)eptr)[E + i];
    }
    int pos = atomicAdd(&cur[dst >> 8], 1);
    ebuk[pos] = (src << 8) | (dst & 255);
  }
}

// ---------------- per-bucket LDS counting sort -> csrc ----------------
__global__ __launch_bounds__(256) void k_bsort(const int* __restrict__ ebuk,
                                               const int* __restrict__ rp,
                                               int* __restrict__ csrc, int n, int nbuk) {
  __shared__ int curs[256];
  __shared__ int outb[CAP2];
  int b = blockIdx.x, t = threadIdx.x;
  int v0 = b << 8;
  int v1 = min(v0 + 256, n);
  int base = rp[v0];
  int cnt = rp[v1] - base;
  int nn = v1 - v0;
  if (t < nn) curs[t] = rp[v0 + t] - base;
  __syncthreads();
  if (cnt <= CAP2) {
    for (int i = t; i < cnt; i += 256) {
      int e = ebuk[base + i];
      int slot = atomicAdd(&curs[e & 255], 1);
      outb[slot] = e >> 8;
    }
    __syncthreads();
    for (int i = t; i < cnt; i += 256) csrc[base + i] = outb[i];
  } else {
    for (int i = t; i < cnt; i += 256) {
      int e = ebuk[base + i];
      int slot = atomicAdd(&curs[e & 255], 1);
      csrc[base + slot] = e >> 8;
    }
  }
}

// fallback scatter (only if nbuk > MAXBUK; never for this dataset)
__global__ void k_scatter_fb(const void* __restrict__ eptr, int E, const int* __restrict__ flag,
                             const int* __restrict__ rp, int* __restrict__ cur,
                             int* __restrict__ csrc) {
  int i = blockIdx.x * 256 + threadIdx.x;
  if (i >= E) return;
  bool f = (*flag) != 0;
  int src, dst;
  if (f) {
    src = (int)((const long long*)eptr)[i];
    dst = (int)((const long long*)eptr)[E + i];
  } else {
    src = ((const int*)eptr)[i];
    dst = ((const int*)eptr)[E + i];
  }
  int pos = rp[dst] + atomicAdd(&cur[dst], 1);
  csrc[pos] = src;
}

// ---------------- x -> bf16, fused x column stats ----------------
__global__ __launch_bounds__(256) void k_cvt_x(const float4* __restrict__ x,
                                               ushort4* __restrict__ xb, int n4,
                                               float* __restrict__ part) {
  int t = threadIdx.x;
  float s[4] = {0, 0, 0, 0}, q[4] = {0, 0, 0, 0};
  for (int i = blockIdx.x * 256 + t; i < n4; i += gridDim.x * 256) {
    float4 a = x[i];
    ushort4 o;
    o.x = f2b(a.x); o.y = f2b(a.y); o.z = f2b(a.z); o.w = f2b(a.w);
    xb[i] = o;
    s[0] += a.x; s[1] += a.y; s[2] += a.z; s[3] += a.w;
    q[0] = fmaf(a.x, a.x, q[0]); q[1] = fmaf(a.y, a.y, q[1]);
    q[2] = fmaf(a.z, a.z, q[2]); q[3] = fmaf(a.w, a.w, q[3]);
  }
  // col phase: (i % 32)*4 == (t % 32)*4 for all iterations (stride % 32 == 0)
  __shared__ float sh[256][8];
#pragma unroll
  for (int j = 0; j < 4; ++j) { sh[t][j] = s[j]; sh[t][4 + j] = q[j]; }
  __syncthreads();
  if (t < 32) {
#pragma unroll
    for (int g = 1; g < 8; ++g)
#pragma unroll
      for (int j = 0; j < 4; ++j) {
        s[j] += sh[g * 32 + t][j];
        q[j] += sh[g * 32 + t][4 + j];
      }
    float* pp = part + (size_t)(blockIdx.x & 63) * 768;
#pragma unroll
    for (int j = 0; j < 4; ++j) {
      atomicAdd(&pp[(t * 4 + j) * 2], s[j]);
      atomicAdd(&pp[(t * 4 + j) * 2 + 1], q[j]);
    }
  }
}

// ---------------- W1/W2 -> pre-swizzled bf16 LDS image ----------------
__global__ void k_prep_w(const float* __restrict__ W1, const float* __restrict__ W2,
                         unsigned short* __restrict__ wimg) {
  int i = blockIdx.x * 256 + threadIdx.x;  // 0..32767
  if (i >= 32768) return;
  int wsel = i >> 14;
  int j = i & 16383;
  int k = j >> 7, col = j & 127;
  float v = (wsel ? W2 : W1)[j];
  int chunk = (k >> 3) ^ (col & 7);
  wimg[wsel * 16384 + col * 128 + chunk * 8 + (k & 7)] = f2b(v);
}

// ---------------- MFMA GEMM: H = bf16((A @ W) * dinv[row]) ----------------
__global__ __launch_bounds__(256) void k_gemm(const unsigned short* __restrict__ Ab,
                                              const unsigned short* __restrict__ Wimg,
                                              const float* __restrict__ dinv,
                                              unsigned short* __restrict__ H, int n) {
  __shared__ __align__(16) unsigned short Wl[16384];
  int t = threadIdx.x, lane = t & 63, w = t >> 6;
#pragma unroll
  for (int i = t; i < 2048; i += 256) ((int4*)Wl)[i] = ((const int4*)Wimg)[i];
  __syncthreads();
  int rowBase = blockIdx.x * 128 + w * 32;
  int r16 = lane & 15, half = lane >> 4;
  f32x4 acc[2][8];
#pragma unroll
  for (int m = 0; m < 2; ++m)
#pragma unroll
    for (int nn = 0; nn < 8; ++nn) acc[m][nn] = (f32x4){0.f, 0.f, 0.f, 0.f};
#pragma unroll
  for (int ks = 0; ks < 4; ++ks) {
    bf16x8 a[2];
#pragma unroll
    for (int m = 0; m < 2; ++m) {
      int r = rowBase + m * 16 + r16;
      if (r >= n) r = n - 1;
      a[m] = *(const bf16x8*)(Ab + (size_t)r * DD + ks * 32 + half * 8);
    }
#pragma unroll
    for (int nn = 0; nn < 8; ++nn) {
      int col = nn * 16 + r16;
      int chunk = (ks * 4 + half) ^ (col & 7);
      bf16x8 b = *(const bf16x8*)(Wl + col * 128 + chunk * 8);
      acc[0][nn] = __builtin_amdgcn_mfma_f32_16x16x32_bf16(a[0], b, acc[0][nn], 0, 0, 0);
      acc[1][nn] = __builtin_amdgcn_mfma_f32_16x16x32_bf16(a[1], b, acc[1][nn], 0, 0, 0);
    }
  }
#pragma unroll
  for (int m = 0; m < 2; ++m) {
    int rb = rowBase + m * 16 + half * 4;
    float dv[4];
#pragma unroll
    for (int i = 0; i < 4; ++i) dv[i] = (rb + i < n) ? dinv[rb + i] : 0.f;
#pragma unroll
    for (int nn = 0; nn < 8; ++nn) {
      int col = nn * 16 + r16;
#pragma unroll
      for (int i = 0; i < 4; ++i) {
        int r = rb + i;
        if (r < n) H[(size_t)r * DD + col] = f2b(acc[m][nn][i] * dv[i]);
      }
    }
  }
}

// ---------------- aggregation (bf16 gather) + fused column stats ----------------
__global__ __launch_bounds__(256) void k_agg(const unsigned short* __restrict__ hs,
                                             const float* __restrict__ dinv,
                                             const float* __restrict__ b,
                                             const int* __restrict__ rp,
                                             const int* __restrict__ csrc,
                                             unsigned short* __restrict__ y, int n,
                                             float* __restrict__ part, int cb) {
  __shared__ float sh[4][64][4];
  int wid = threadIdx.x >> 6, lane = threadIdx.x & 63;
  int v = blockIdx.x * 4 + wid;
  bool ok = v < n;
  int e0 = 0, e1 = 0;
  if (ok) { e0 = rp[v]; e1 = rp[v + 1]; }
  const uint32* H = (const uint32*)hs;
  float ax = 0.f, ay = 0.f;
  for (int eb = e0; eb < e1; eb += 64) {
    int ec = e1 - eb;
    if (ec > 64) ec = 64;
    int ul = (eb + lane < e1) ? csrc[eb + lane] : 0;
    for (int tt = 0; tt < ec; ++tt) {
      int u = __shfl(ul, tt);
      uint32 hv = H[(size_t)u * 64 + lane];
      ax += b2f_lo(hv);
      ay += b2f_hi(hv);
    }
  }
  float ox = 0.f, oy = 0.f;
  if (ok) {
    uint32 hv = H[(size_t)v * 64 + lane];
    float dv = dinv[v];
    float2 bb = ((const float2*)b)[lane];
    ox = fmaxf(fmaf(dv, ax + b2f_lo(hv), bb.x), 0.f);
    oy = fmaxf(fmaf(dv, ay + b2f_hi(hv), bb.y), 0.f);
    uint32 o = (uint32)f2b(ox) | ((uint32)f2b(oy) << 16);
    ((uint32*)y)[(size_t)v * 64 + lane] = o;
  }
  sh[wid][lane][0] = ox;
  sh[wid][lane][1] = oy;
  sh[wid][lane][2] = ox * ox;
  sh[wid][lane][3] = oy * oy;
  __syncthreads();
  if (threadIdx.x < 64) {
    int uc = threadIdx.x;
    float s0 = 0.f, s1 = 0.f, q0 = 0.f, q1 = 0.f;
#pragma unroll
    for (int k2 = 0; k2 < 4; ++k2) {
      s0 += sh[k2][uc][0];
      s1 += sh[k2][uc][1];
      q0 += sh[k2][uc][2];
      q1 += sh[k2][uc][3];
    }
    float* pp = part + (size_t)(blockIdx.x & 63) * 768 + (cb + uc * 2) * 2;
    atomicAdd(&pp[0], s0);
    atomicAdd(&pp[1], q0);
    atomicAdd(&pp[2], s1);
    atomicAdd(&pp[3], q1);
  }
}

// ---------------- BN fold: reduce partials, compute scale/shift + folded bias ----------------
__global__ void k_fold_a(const float* __restrict__ part, const float* __restrict__ gamma,
                         const float* __restrict__ beta, const float* __restrict__ Wo,
                         const float* __restrict__ bo, float* __restrict__ aS,
                         float* __restrict__ boP, int n) {
  __shared__ float cSh[384];
  int t = threadIdx.x;  // 0..383
  float s = 0.f, q = 0.f;
  for (int r = 0; r < 64; ++r) {
    s += part[r * 768 + t * 2];
    q += part[r * 768 + t * 2 + 1];
  }
  float inv_n = 1.0f / (float)n;
  float mu = s * inv_n;
  float var = q * inv_n - mu * mu;
  float a = gamma[t] * rsqrtf(var + 1e-5f);
  aS[t] = a;
  cSh[t] = beta[t] - mu * a;
  __syncthreads();
  if (t < DD) {
    float sb = bo[t];
    for (int k = 0; k < 384; ++k) sb = fmaf(cSh[k], Wo[k * DD + t], sb);
    boP[t] = sb;
  }
}

// ---------------- WoP image (bf16, pre-swizzled) ----------------
__global__ void k_foldw(const float* __restrict__ aS, const float* __restrict__ Wo,
                        unsigned short* __restrict__ wopimg) {
  int i = blockIdx.x * 256 + threadIdx.x;  // 0..49151
  if (i >= 49152) return;
  int krow = i >> 7, col = i & 127;
  float v = aS[krow] * Wo[i];
  int p = krow >> 7, kk = krow & 127;
  int chunk = (kk >> 3) ^ (col & 7);
  wopimg[p * 16384 + col * 128 + chunk * 8 + (kk & 7)] = f2b(v);
}

// ---------------- final MFMA GEMM: out = [xb|y1|y2] @ WoP + boP (f32 out) ----------------
__global__ __launch_bounds__(256) void k_gemm_out(const unsigned short* __restrict__ xb,
                                                  const unsigned short* __restrict__ y1,
                                                  const unsigned short* __restrict__ y2,
                                                  const unsigned short* __restrict__ Wimg3,
                                                  const float* __restrict__ boP,
                                                  float* __restrict__ out, int n) {
  __shared__ __align__(16) unsigned short Wl[16384];
  int t = threadIdx.x, lane = t & 63, w = t >> 6;
  int rowBase = blockIdx.x * 128 + w * 32;
  int r16 = lane & 15, half = lane >> 4;
  f32x4 acc[2][8];
#pragma unroll
  for (int m = 0; m < 2; ++m)
#pragma unroll
    for (int nn = 0; nn < 8; ++nn) acc[m][nn] = (f32x4){0.f, 0.f, 0.f, 0.f};
  for (int p = 0; p < 3; ++p) {
    const unsigned short* Ab = (p == 0) ? xb : (p == 1) ? y1 : y2;
    __syncthreads();
#pragma unroll
    for (int i = t; i < 2048; i += 256) ((int4*)Wl)[i] = ((const int4*)(Wimg3 + p * 16384))[i];
    __syncthreads();
#pragma unroll
    for (int ks = 0; ks < 4; ++ks) {
      bf16x8 a[2];
#pragma unroll
      for (int m = 0; m < 2; ++m) {
        int r = rowBase + m * 16 + r16;
        if (r >= n) r = n - 1;
        a[m] = *(const bf16x8*)(Ab + (size_t)r * DD + ks * 32 + half * 8);
      }
#pragma unroll
      for (int nn = 0; nn < 8; ++nn) {
        int col = nn * 16 + r16;
        int chunk = (ks * 4 + half) ^ (col & 7);
        bf16x8 b = *(const bf16x8*)(Wl + col * 128 + chunk * 8);
        acc[0][nn] = __builtin_amdgcn_mfma_f32_16x16x32_bf16(a[0], b, acc[0][nn], 0, 0, 0);
        acc[1][nn] = __builtin_amdgcn_mfma_f32_16x16x32_bf16(a[1], b, acc[1][nn], 0, 0, 0);
      }
    }
  }
#pragma unroll
  for (int m = 0; m < 2; ++m) {
    int rb = rowBase + m * 16 + half * 4;
#pragma unroll
    for (int nn = 0; nn < 8; ++nn) {
      int col = nn * 16 + r16;
      float bb = boP[col];
#pragma unroll
      for (int i = 0; i < 4; ++i) {
        int r = rb + i;
        if (r < n) out[(size_t)r * DD + col] = acc[m][nn][i] + bb;
      }
    }
  }
}

extern "C" void kernel_launch(void* const* d_in, const int* in_sizes, int n_in,
                              void* d_out, int out_size, void* d_ws, size_t ws_size,
                              hipStream_t stream) {
  const float* x = (const float*)d_in[0];
  const void* ept = d_in[1];
  const float* W1 = (const float*)d_in[2];
  const float* b1 = (const float*)d_in[3];
  const float* W2 = (const float*)d_in[4];
  const float* b2 = (const float*)d_in[5];
  const float* gamma = (const float*)d_in[6];
  const float* beta = (const float*)d_in[7];
  const float* Wo = (const float*)d_in[8];
  const float* bo = (const float*)d_in[9];
  float* out = (float*)d_out;
  int N = in_sizes[0] / DD;
  int E = in_sizes[1] / 2;
  int nbuk = (N + 255) >> 8;

  char* w = (char*)d_ws;
  size_t off = 0;
  auto alloc = [&](size_t bytes) {
    void* p = w + off;
    off = (off + bytes + 255) & ~(size_t)255;
    return p;
  };
  float* dinv = (float*)alloc((size_t)N * 4);
  int* degi = (int*)alloc((size_t)N * 4);
  int* rp = (int*)alloc((size_t)(N + 1) * 4);
  int* csrc = (int*)alloc((size_t)E * 4);
  int* ebuk = (int*)alloc((size_t)E * 4);
  int* histT = (int*)alloc((size_t)MAXBUK * NBLK * 4);
  int* offs = (int*)alloc((size_t)MAXBUK * NBLK * 4);
  unsigned short* xb = (unsigned short*)alloc((size_t)N * DD * 2);
  unsigned short* h = (unsigned short*)alloc((size_t)N * DD * 2);
  unsigned short* y1 = (unsigned short*)alloc((size_t)N * DD * 2);
  unsigned short* y2 = (unsigned short*)alloc((size_t)N * DD * 2);
  unsigned short* wimg = (unsigned short*)alloc(32768 * 2);
  unsigned short* wopimg = (unsigned short*)alloc(49152 * 2);
  float* part = (float*)alloc((size_t)64 * 768 * 4);
  float* aS = (float*)alloc(384 * 4);
  float* boP = (float*)alloc(DD * 4);
  int* flag = (int*)alloc(4);
  int nbs = (N + 255) / 256;
  int* bsum = (int*)alloc((size_t)(nbs + 1) * 4);

  int dohist = (nbuk <= MAXBUK) ? 1 : 0;

  hipMemsetAsync(degi, 0, (size_t)N * 4, stream);
  hipMemsetAsync(part, 0, (size_t)64 * 768 * 4, stream);

  int eb = (E + 255) / 256;
  int nb = (N + 255) / 256;
  k_detect<<<1, 256, 0, stream>>>((const int*)ept, E, flag);
  k_hist<<<NBLK, 256, 0, stream>>>(ept, E, flag, degi, histT, nbuk, dohist);
  k_dinv<<<nb, 256, 0, stream>>>(degi, dinv, N);
  k_scan1<<<nbs, 256, 0, stream>>>(degi, rp, bsum, N);
  k_scan2<<<1, 1024, 0, stream>>>(bsum, bsum, nbs);
  k_scan3<<<nbs, 256, 0, stream>>>(rp, bsum, N, nbs);
  if (dohist) {
    k_bscan<<<(nbuk + 3) / 4, 256, 0, stream>>>(histT, rp, offs, nbuk);
    k_place<<<NBLK, 256, 0, stream>>>(ept, E, flag, offs, ebuk, nbuk);
    k_bsort<<<nbuk, 256, 0, stream>>>(ebuk, rp, csrc, N, nbuk);
  } else {
    hipMemsetAsync(degi, 0, (size_t)N * 4, stream);
    k_scatter_fb<<<eb, 256, 0, stream>>>(ept, E, flag, rp, degi, csrc);
  }

  int n4 = N * DD / 4;
  k_cvt_x<<<1024, 256, 0, stream>>>((const float4*)x, (ushort4*)xb, n4, part);
  k_prep_w<<<128, 256, 0, stream>>>(W1, W2, wimg);

  int gb = (N + 127) / 128;
  int ab = (N + 3) / 4;
  k_gemm<<<gb, 256, 0, stream>>>(xb, wimg, dinv, h, N);
  k_agg<<<ab, 256, 0, stream>>>(h, dinv, b1, rp, csrc, y1, N, part, 128);
  k_gemm<<<gb, 256, 0, stream>>>(y1, wimg + 16384, dinv, h, N);
  k_agg<<<ab, 256, 0, stream>>>(h, dinv, b2, rp, csrc, y2, N, part, 256);

  k_fold_a<<<1, 384, 0, stream>>>(part, gamma, beta, Wo, bo, aS, boP, N);
  k_foldw<<<192, 256, 0, stream>>>(aS, Wo, wopimg);
  k_gemm_out<<<gb, 256, 0, stream>>>(xb, y1, y2, wopimg, boP, out, N);
}

// Round 5
// 431.957 us; speedup vs baseline: 2.2766x; 1.3956x over previous
//
#include <hip/hip_runtime.h>
#include <hip/hip_bf16.h>

#define DD 128
#define NBLK 256     // blocks for hist/place passes
#define MAXBUK 1024  // max dst-buckets (256 nodes each) supported by LDS path
#define CAP2 12288   // max edges per bucket for LDS sort staging

typedef __attribute__((ext_vector_type(8))) short bf16x8;
typedef __attribute__((ext_vector_type(4))) float f32x4;
typedef unsigned int uint32;

__device__ __forceinline__ unsigned short f2b(float f) {
  __hip_bfloat16 h = __float2bfloat16(f);
  unsigned short u;
  __builtin_memcpy(&u, &h, 2);
  return u;
}
__device__ __forceinline__ float b2f_lo(uint32 v) { return __uint_as_float(v << 16); }
__device__ __forceinline__ float b2f_hi(uint32 v) { return __uint_as_float(v & 0xffff0000u); }

// ---------------- edge dtype detect ----------------
__global__ void k_detect(const int* __restrict__ e, int pairs, int* __restrict__ flag) {
  __shared__ int nz;
  if (threadIdx.x == 0) nz = 0;
  __syncthreads();
  int samples = pairs < 4096 ? pairs : 4096;
  for (int i = threadIdx.x; i < samples; i += blockDim.x)
    if (e[2 * i + 1] != 0) atomicAdd(&nz, 1);
  __syncthreads();
  if (threadIdx.x == 0) *flag = (nz == 0) ? 1 : 0;  // 1 => underlying int64
}

// ---------------- degree count + per-block bucket histogram ----------------
__global__ __launch_bounds__(256) void k_hist(const void* __restrict__ eptr, int E,
                                              const int* __restrict__ flag,
                                              int* __restrict__ degi, int* __restrict__ histT,
                                              int nbuk, int dohist) {
  __shared__ int hist[MAXBUK];
  int t = threadIdx.x, blk = blockIdx.x;
  if (dohist)
    for (int b = t; b < nbuk; b += 256) hist[b] = 0;
  __syncthreads();
  int chunk = (E + NBLK - 1) / NBLK;
  int i0 = blk * chunk, i1 = min(E, i0 + chunk);
  bool f = (*flag) != 0;
  for (int i = i0 + t; i < i1; i += 256) {
    int dst = f ? (int)((const long long*)eptr)[E + i] : ((const int*)eptr)[E + i];
    atomicAdd(&degi[dst], 1);
    if (dohist) atomicAdd(&hist[dst >> 8], 1);
  }
  __syncthreads();
  if (dohist)
    for (int b = t; b < nbuk; b += 256) histT[b * NBLK + blk] = hist[b];
}

__global__ void k_dinv(const int* __restrict__ degi, float* __restrict__ dinv, int n) {
  int i = blockIdx.x * 256 + threadIdx.x;
  if (i < n) dinv[i] = rsqrtf((float)degi[i] + 1.0f);
}

// ---------------- 3-phase parallel exclusive scan (rp over degi) ----------------
__global__ void k_scan1(const int* __restrict__ cnt, int* __restrict__ rp,
                        int* __restrict__ bsum, int n) {
  __shared__ int ws[4];
  int t = threadIdx.x, lane = t & 63, wv = t >> 6;
  int i = blockIdx.x * 256 + t;
  int v = (i < n) ? cnt[i] : 0;
  int incl = v;
#pragma unroll
  for (int o = 1; o < 64; o <<= 1) {
    int u = __shfl_up(incl, o);
    if (lane >= o) incl += u;
  }
  if (lane == 63) ws[wv] = incl;
  __syncthreads();
  int off = 0;
  for (int k = 0; k < wv; ++k) off += ws[k];
  if (i < n) rp[i] = incl - v + off;
  if (t == 255) bsum[blockIdx.x] = off + incl;
}

__global__ void k_scan2(const int* __restrict__ cnt, int* __restrict__ rp, int n) {
  __shared__ int wsum[16];
  __shared__ int ctot;
  int t = threadIdx.x, lane = t & 63, wid = t >> 6;
  int base = 0;
  for (int start = 0; start < n; start += 1024) {
    int i = start + t;
    int v = (i < n) ? cnt[i] : 0;
    int incl = v;
#pragma unroll
    for (int o = 1; o < 64; o <<= 1) {
      int u = __shfl_up(incl, o);
      if (lane >= o) incl += u;
    }
    if (lane == 63) wsum[wid] = incl;
    __syncthreads();
    if (t < 16) {
      int s = wsum[t];
      int e = s;
#pragma unroll
      for (int o = 1; o < 16; o <<= 1) {
        int u = __shfl_up(e, o, 16);
        if (t >= o) e += u;
      }
      wsum[t] = e - s;
      if (t == 15) ctot = e;
    }
    __syncthreads();
    if (i < n) rp[i] = base + wsum[wid] + incl - v;
    base += ctot;
    __syncthreads();
  }
  if (t == 0) rp[n] = base;
}

__global__ void k_scan3(int* __restrict__ rp, const int* __restrict__ bsumex, int n, int nb) {
  int i = blockIdx.x * 256 + threadIdx.x;
  if (i < n) rp[i] += bsumex[blockIdx.x];
  if (i == 0) rp[n] = bsumex[nb];
}

// ---------------- bucket scan: offs[b][blk] = global write base ----------------
__global__ void k_bscan(const int* __restrict__ histT, const int* __restrict__ rp,
                        int* __restrict__ offs, int nbuk) {
  int t = threadIdx.x, lane = t & 63, wid = t >> 6;
  int b = blockIdx.x * 4 + wid;
  if (b >= nbuk) return;
  int base = rp[b << 8];
  int idx = b * NBLK + lane * 4;
  int v0 = histT[idx], v1 = histT[idx + 1], v2 = histT[idx + 2], v3 = histT[idx + 3];
  int lsum = v0 + v1 + v2 + v3;
  int incl = lsum;
#pragma unroll
  for (int o = 1; o < 64; o <<= 1) {
    int u = __shfl_up(incl, o);
    if (lane >= o) incl += u;
  }
  int excl = base + incl - lsum;
  offs[idx] = excl;
  offs[idx + 1] = excl + v0;
  offs[idx + 2] = excl + v0 + v1;
  offs[idx + 3] = excl + v0 + v1 + v2;
}

// ---------------- place edges into bucket regions (block-contiguous runs) ----------------
__global__ __launch_bounds__(256) void k_place(const void* __restrict__ eptr, int E,
                                               const int* __restrict__ flag,
                                               const int* __restrict__ offs,
                                               int* __restrict__ ebuk, int nbuk) {
  __shared__ int cur[MAXBUK];
  int t = threadIdx.x, blk = blockIdx.x;
  for (int b = t; b < nbuk; b += 256) cur[b] = offs[b * NBLK + blk];
  __syncthreads();
  int chunk = (E + NBLK - 1) / NBLK;
  int i0 = blk * chunk, i1 = min(E, i0 + chunk);
  bool f = (*flag) != 0;
  for (int i = i0 + t; i < i1; i += 256) {
    int src, dst;
    if (f) {
      src = (int)((const long long*)eptr)[i];
      dst = (int)((const long long*)eptr)[E + i];
    } else {
      src = ((const int*)eptr)[i];
      dst = ((const int*)eptr)[E + i];
    }
    int pos = atomicAdd(&cur[dst >> 8], 1);
    ebuk[pos] = (src << 8) | (dst & 255);
  }
}

// ---------------- per-bucket LDS counting sort -> csrc ----------------
__global__ __launch_bounds__(256) void k_bsort(const int* __restrict__ ebuk,
                                               const int* __restrict__ rp,
                                               int* __restrict__ csrc, int n, int nbuk) {
  __shared__ int curs[256];
  __shared__ int outb[CAP2];
  int b = blockIdx.x, t = threadIdx.x;
  int v0 = b << 8;
  int v1 = min(v0 + 256, n);
  int base = rp[v0];
  int cnt = rp[v1] - base;
  int nn = v1 - v0;
  if (t < nn) curs[t] = rp[v0 + t] - base;
  __syncthreads();
  if (cnt <= CAP2) {
    for (int i = t; i < cnt; i += 256) {
      int e = ebuk[base + i];
      int slot = atomicAdd(&curs[e & 255], 1);
      outb[slot] = e >> 8;
    }
    __syncthreads();
    for (int i = t; i < cnt; i += 256) csrc[base + i] = outb[i];
  } else {
    for (int i = t; i < cnt; i += 256) {
      int e = ebuk[base + i];
      int slot = atomicAdd(&curs[e & 255], 1);
      csrc[base + slot] = e >> 8;
    }
  }
}

// fallback scatter (only if nbuk > MAXBUK; never for this dataset)
__global__ void k_scatter_fb(const void* __restrict__ eptr, int E, const int* __restrict__ flag,
                             const int* __restrict__ rp, int* __restrict__ cur,
                             int* __restrict__ csrc) {
  int i = blockIdx.x * 256 + threadIdx.x;
  if (i >= E) return;
  bool f = (*flag) != 0;
  int src, dst;
  if (f) {
    src = (int)((const long long*)eptr)[i];
    dst = (int)((const long long*)eptr)[E + i];
  } else {
    src = ((const int*)eptr)[i];
    dst = ((const int*)eptr)[E + i];
  }
  int pos = rp[dst] + atomicAdd(&cur[dst], 1);
  csrc[pos] = src;
}

// ---------------- x -> bf16, fused x column stats ----------------
__global__ __launch_bounds__(256) void k_cvt_x(const float4* __restrict__ x,
                                               ushort4* __restrict__ xb, int n4,
                                               float* __restrict__ part) {
  int t = threadIdx.x;
  float s[4] = {0, 0, 0, 0}, q[4] = {0, 0, 0, 0};
  for (int i = blockIdx.x * 256 + t; i < n4; i += gridDim.x * 256) {
    float4 a = x[i];
    ushort4 o;
    o.x = f2b(a.x); o.y = f2b(a.y); o.z = f2b(a.z); o.w = f2b(a.w);
    xb[i] = o;
    s[0] += a.x; s[1] += a.y; s[2] += a.z; s[3] += a.w;
    q[0] = fmaf(a.x, a.x, q[0]); q[1] = fmaf(a.y, a.y, q[1]);
    q[2] = fmaf(a.z, a.z, q[2]); q[3] = fmaf(a.w, a.w, q[3]);
  }
  __shared__ float sh[256][8];
#pragma unroll
  for (int j = 0; j < 4; ++j) { sh[t][j] = s[j]; sh[t][4 + j] = q[j]; }
  __syncthreads();
  if (t < 32) {
#pragma unroll
    for (int g = 1; g < 8; ++g)
#pragma unroll
      for (int j = 0; j < 4; ++j) {
        s[j] += sh[g * 32 + t][j];
        q[j] += sh[g * 32 + t][4 + j];
      }
    float* pp = part + (size_t)(blockIdx.x & 63) * 768;
#pragma unroll
    for (int j = 0; j < 4; ++j) {
      atomicAdd(&pp[(t * 4 + j) * 2], s[j]);
      atomicAdd(&pp[(t * 4 + j) * 2 + 1], q[j]);
    }
  }
}

// ---------------- W1/W2 -> pre-swizzled bf16 LDS image ----------------
__global__ void k_prep_w(const float* __restrict__ W1, const float* __restrict__ W2,
                         unsigned short* __restrict__ wimg) {
  int i = blockIdx.x * 256 + threadIdx.x;  // 0..32767
  if (i >= 32768) return;
  int wsel = i >> 14;
  int j = i & 16383;
  int k = j >> 7, col = j & 127;
  float v = (wsel ? W2 : W1)[j];
  int chunk = (k >> 3) ^ (col & 7);
  wimg[wsel * 16384 + col * 128 + chunk * 8 + (k & 7)] = f2b(v);
}

// ---------------- MFMA GEMM: H = bf16((A @ W) * dinv[row]) ----------------
__global__ __launch_bounds__(256) void k_gemm(const unsigned short* __restrict__ Ab,
                                              const unsigned short* __restrict__ Wimg,
                                              const float* __restrict__ dinv,
                                              unsigned short* __restrict__ H, int n) {
  __shared__ __align__(16) unsigned short Wl[16384];
  int t = threadIdx.x, lane = t & 63, w = t >> 6;
#pragma unroll
  for (int i = t; i < 2048; i += 256) ((int4*)Wl)[i] = ((const int4*)Wimg)[i];
  __syncthreads();
  int rowBase = blockIdx.x * 128 + w * 32;
  int r16 = lane & 15, half = lane >> 4;
  f32x4 acc[2][8];
#pragma unroll
  for (int m = 0; m < 2; ++m)
#pragma unroll
    for (int nn = 0; nn < 8; ++nn) acc[m][nn] = (f32x4){0.f, 0.f, 0.f, 0.f};
#pragma unroll
  for (int ks = 0; ks < 4; ++ks) {
    bf16x8 a[2];
#pragma unroll
    for (int m = 0; m < 2; ++m) {
      int r = rowBase + m * 16 + r16;
      if (r >= n) r = n - 1;
      a[m] = *(const bf16x8*)(Ab + (size_t)r * DD + ks * 32 + half * 8);
    }
#pragma unroll
    for (int nn = 0; nn < 8; ++nn) {
      int col = nn * 16 + r16;
      int chunk = (ks * 4 + half) ^ (col & 7);
      bf16x8 b = *(const bf16x8*)(Wl + col * 128 + chunk * 8);
      acc[0][nn] = __builtin_amdgcn_mfma_f32_16x16x32_bf16(a[0], b, acc[0][nn], 0, 0, 0);
      acc[1][nn] = __builtin_amdgcn_mfma_f32_16x16x32_bf16(a[1], b, acc[1][nn], 0, 0, 0);
    }
  }
#pragma unroll
  for (int m = 0; m < 2; ++m) {
    int rb = rowBase + m * 16 + half * 4;
    float dv[4];
#pragma unroll
    for (int i = 0; i < 4; ++i) dv[i] = (rb + i < n) ? dinv[rb + i] : 0.f;
#pragma unroll
    for (int nn = 0; nn < 8; ++nn) {
      int col = nn * 16 + r16;
#pragma unroll
      for (int i = 0; i < 4; ++i) {
        int r = rb + i;
        if (r < n) H[(size_t)r * DD + col] = f2b(acc[m][nn][i] * dv[i]);
      }
    }
  }
}

// ---------------- aggregation: 4 edges x 16 lanes x 16B gather + fused stats ----------------
__global__ __launch_bounds__(256) void k_agg(const unsigned short* __restrict__ hs,
                                             const float* __restrict__ dinv,
                                             const float* __restrict__ b,
                                             const int* __restrict__ rp,
                                             const int* __restrict__ csrc,
                                             unsigned short* __restrict__ y, int n,
                                             float* __restrict__ part, int cb) {
  __shared__ float sh_s[4][128];
  __shared__ float sh_q[4][128];
  int wid = threadIdx.x >> 6, lane = threadIdx.x & 63;
  int eidx = lane >> 4;  // 0..3: which edge of the 4-group
  int seg = lane & 15;   // 0..15: 16B segment of the row
  int v = blockIdx.x * 4 + wid;
  bool ok = v < n;
  int e0 = 0, e1 = 0;
  if (ok) { e0 = rp[v]; e1 = rp[v + 1]; }
  const uint4* H4 = (const uint4*)hs;  // one row = 16 uint4
  float acc[8];
#pragma unroll
  for (int j = 0; j < 8; ++j) acc[j] = 0.f;
  for (int eb = e0; eb < e1; eb += 64) {
    int ec = e1 - eb;
    if (ec > 64) ec = 64;
    int ul = (eb + lane < e1) ? csrc[eb + lane] : 0;
    for (int cc = 0; cc < ec; cc += 8) {
      int u0 = __shfl(ul, cc + eidx);
      int u1 = __shfl(ul, cc + 4 + eidx);
      bool va0 = (cc + eidx) < ec;
      bool va1 = (cc + 4 + eidx) < ec;
      uint4 h0 = H4[(size_t)(va0 ? u0 : 0) * 16 + seg];
      uint4 h1 = H4[(size_t)(va1 ? u1 : 0) * 16 + seg];
      if (va0) {
        acc[0] += b2f_lo(h0.x); acc[1] += b2f_hi(h0.x);
        acc[2] += b2f_lo(h0.y); acc[3] += b2f_hi(h0.y);
        acc[4] += b2f_lo(h0.z); acc[5] += b2f_hi(h0.z);
        acc[6] += b2f_lo(h0.w); acc[7] += b2f_hi(h0.w);
      }
      if (va1) {
        acc[0] += b2f_lo(h1.x); acc[1] += b2f_hi(h1.x);
        acc[2] += b2f_lo(h1.y); acc[3] += b2f_hi(h1.y);
        acc[4] += b2f_lo(h1.z); acc[5] += b2f_hi(h1.z);
        acc[6] += b2f_lo(h1.w); acc[7] += b2f_hi(h1.w);
      }
    }
  }
  // butterfly-reduce across the 4 edge-groups (lanes differing in bits 4,5)
#pragma unroll
  for (int j = 0; j < 8; ++j) {
    acc[j] += __shfl_xor(acc[j], 16);
    acc[j] += __shfl_xor(acc[j], 32);
  }
  float o[8];
  if (ok) {
    uint4 self = H4[(size_t)v * 16 + seg];
    float sf[8] = {b2f_lo(self.x), b2f_hi(self.x), b2f_lo(self.y), b2f_hi(self.y),
                   b2f_lo(self.z), b2f_hi(self.z), b2f_lo(self.w), b2f_hi(self.w)};
    float dv = dinv[v];
    float4 bb0 = ((const float4*)b)[seg * 2];
    float4 bb1 = ((const float4*)b)[seg * 2 + 1];
    float bv[8] = {bb0.x, bb0.y, bb0.z, bb0.w, bb1.x, bb1.y, bb1.z, bb1.w};
#pragma unroll
    for (int j = 0; j < 8; ++j)
      o[j] = fmaxf(fmaf(dv, acc[j] + sf[j], bv[j]), 0.f);
    if (eidx == 0) {
      uint4 ov;
      ov.x = (uint32)f2b(o[0]) | ((uint32)f2b(o[1]) << 16);
      ov.y = (uint32)f2b(o[2]) | ((uint32)f2b(o[3]) << 16);
      ov.z = (uint32)f2b(o[4]) | ((uint32)f2b(o[5]) << 16);
      ov.w = (uint32)f2b(o[6]) | ((uint32)f2b(o[7]) << 16);
      ((uint4*)y)[(size_t)v * 16 + seg] = ov;
    }
  } else {
#pragma unroll
    for (int j = 0; j < 8; ++j) o[j] = 0.f;
  }
  if (eidx == 0) {
#pragma unroll
    for (int j = 0; j < 8; ++j) {
      sh_s[wid][seg * 8 + j] = o[j];
      sh_q[wid][seg * 8 + j] = o[j] * o[j];
    }
  }
  __syncthreads();
  if (threadIdx.x < 128) {
    int c = threadIdx.x;
    float s = sh_s[0][c] + sh_s[1][c] + sh_s[2][c] + sh_s[3][c];
    float q = sh_q[0][c] + sh_q[1][c] + sh_q[2][c] + sh_q[3][c];
    float* pp = part + (size_t)(blockIdx.x & 63) * 768;
    atomicAdd(&pp[(cb + c) * 2], s);
    atomicAdd(&pp[(cb + c) * 2 + 1], q);
  }
}

// ---------------- BN fold: reduce partials, compute scale/shift + folded bias ----------------
__global__ void k_fold_a(const float* __restrict__ part, const float* __restrict__ gamma,
                         const float* __restrict__ beta, const float* __restrict__ Wo,
                         const float* __restrict__ bo, float* __restrict__ aS,
                         float* __restrict__ boP, int n) {
  __shared__ float cSh[384];
  int t = threadIdx.x;  // 0..383
  float s = 0.f, q = 0.f;
  for (int r = 0; r < 64; ++r) {
    s += part[r * 768 + t * 2];
    q += part[r * 768 + t * 2 + 1];
  }
  float inv_n = 1.0f / (float)n;
  float mu = s * inv_n;
  float var = q * inv_n - mu * mu;
  float a = gamma[t] * rsqrtf(var + 1e-5f);
  aS[t] = a;
  cSh[t] = beta[t] - mu * a;
  __syncthreads();
  if (t < DD) {
    float sb = bo[t];
    for (int k = 0; k < 384; ++k) sb = fmaf(cSh[k], Wo[k * DD + t], sb);
    boP[t] = sb;
  }
}

// ---------------- WoP image (bf16, pre-swizzled) ----------------
__global__ void k_foldw(const float* __restrict__ aS, const float* __restrict__ Wo,
                        unsigned short* __restrict__ wopimg) {
  int i = blockIdx.x * 256 + threadIdx.x;  // 0..49151
  if (i >= 49152) return;
  int krow = i >> 7, col = i & 127;
  float v = aS[krow] * Wo[i];
  int p = krow >> 7, kk = krow & 127;
  int chunk = (kk >> 3) ^ (col & 7);
  wopimg[p * 16384 + col * 128 + chunk * 8 + (kk & 7)] = f2b(v);
}

// ---------------- final MFMA GEMM: out = [xb|y1|y2] @ WoP + boP (f32 out) ----------------
__global__ __launch_bounds__(256) void k_gemm_out(const unsigned short* __restrict__ xb,
                                                  const unsigned short* __restrict__ y1,
                                                  const unsigned short* __restrict__ y2,
                                                  const unsigned short* __restrict__ Wimg3,
                                                  const float* __restrict__ boP,
                                                  float* __restrict__ out, int n) {
  __shared__ __align__(16) unsigned short Wl[16384];
  int t = threadIdx.x, lane = t & 63, w = t >> 6;
  int rowBase = blockIdx.x * 128 + w * 32;
  int r16 = lane & 15, half = lane >> 4;
  f32x4 acc[2][8];
#pragma unroll
  for (int m = 0; m < 2; ++m)
#pragma unroll
    for (int nn = 0; nn < 8; ++nn) acc[m][nn] = (f32x4){0.f, 0.f, 0.f, 0.f};
  for (int p = 0; p < 3; ++p) {
    const unsigned short* Ab = (p == 0) ? xb : (p == 1) ? y1 : y2;
    __syncthreads();
#pragma unroll
    for (int i = t; i < 2048; i += 256) ((int4*)Wl)[i] = ((const int4*)(Wimg3 + p * 16384))[i];
    __syncthreads();
#pragma unroll
    for (int ks = 0; ks < 4; ++ks) {
      bf16x8 a[2];
#pragma unroll
      for (int m = 0; m < 2; ++m) {
        int r = rowBase + m * 16 + r16;
        if (r >= n) r = n - 1;
        a[m] = *(const bf16x8*)(Ab + (size_t)r * DD + ks * 32 + half * 8);
      }
#pragma unroll
      for (int nn = 0; nn < 8; ++nn) {
        int col = nn * 16 + r16;
        int chunk = (ks * 4 + half) ^ (col & 7);
        bf16x8 b = *(const bf16x8*)(Wl + col * 128 + chunk * 8);
        acc[0][nn] = __builtin_amdgcn_mfma_f32_16x16x32_bf16(a[0], b, acc[0][nn], 0, 0, 0);
        acc[1][nn] = __builtin_amdgcn_mfma_f32_16x16x32_bf16(a[1], b, acc[1][nn], 0, 0, 0);
      }
    }
  }
#pragma unroll
  for (int m = 0; m < 2; ++m) {
    int rb = rowBase + m * 16 + half * 4;
#pragma unroll
    for (int nn = 0; nn < 8; ++nn) {
      int col = nn * 16 + r16;
      float bb = boP[col];
#pragma unroll
      for (int i = 0; i < 4; ++i) {
        int r = rb + i;
        if (r < n) out[(size_t)r * DD + col] = acc[m][nn][i] + bb;
      }
    }
  }
}

extern "C" void kernel_launch(void* const* d_in, const int* in_sizes, int n_in,
                              void* d_out, int out_size, void* d_ws, size_t ws_size,
                              hipStream_t stream) {
  const float* x = (const float*)d_in[0];
  const void* ept = d_in[1];
  const float* W1 = (const float*)d_in[2];
  const float* b1 = (const float*)d_in[3];
  const float* W2 = (const float*)d_in[4];
  const float* b2 = (const float*)d_in[5];
  const float* gamma = (const float*)d_in[6];
  const float* beta = (const float*)d_in[7];
  const float* Wo = (const float*)d_in[8];
  const float* bo = (const float*)d_in[9];
  float* out = (float*)d_out;
  int N = in_sizes[0] / DD;
  int E = in_sizes[1] / 2;
  int nbuk = (N + 255) >> 8;

  char* w = (char*)d_ws;
  size_t off = 0;
  auto alloc = [&](size_t bytes) {
    void* p = w + off;
    off = (off + bytes + 255) & ~(size_t)255;
    return p;
  };
  float* dinv = (float*)alloc((size_t)N * 4);
  int* degi = (int*)alloc((size_t)N * 4);
  int* rp = (int*)alloc((size_t)(N + 1) * 4);
  int* csrc = (int*)alloc((size_t)E * 4);
  int* ebuk = (int*)alloc((size_t)E * 4);
  int* histT = (int*)alloc((size_t)MAXBUK * NBLK * 4);
  int* offs = (int*)alloc((size_t)MAXBUK * NBLK * 4);
  unsigned short* xb = (unsigned short*)alloc((size_t)N * DD * 2);
  unsigned short* h = (unsigned short*)alloc((size_t)N * DD * 2);
  unsigned short* y1 = (unsigned short*)alloc((size_t)N * DD * 2);
  unsigned short* y2 = (unsigned short*)alloc((size_t)N * DD * 2);
  unsigned short* wimg = (unsigned short*)alloc(32768 * 2);
  unsigned short* wopimg = (unsigned short*)alloc(49152 * 2);
  float* part = (float*)alloc((size_t)64 * 768 * 4);
  float* aS = (float*)alloc(384 * 4);
  float* boP = (float*)alloc(DD * 4);
  int* flag = (int*)alloc(4);
  int nbs = (N + 255) / 256;
  int* bsum = (int*)alloc((size_t)(nbs + 1) * 4);

  int dohist = (nbuk <= MAXBUK) ? 1 : 0;

  hipMemsetAsync(degi, 0, (size_t)N * 4, stream);
  hipMemsetAsync(part, 0, (size_t)64 * 768 * 4, stream);

  int eb = (E + 255) / 256;
  int nb = (N + 255) / 256;
  k_detect<<<1, 256, 0, stream>>>((const int*)ept, E, flag);
  k_hist<<<NBLK, 256, 0, stream>>>(ept, E, flag, degi, histT, nbuk, dohist);
  k_dinv<<<nb, 256, 0, stream>>>(degi, dinv, N);
  k_scan1<<<nbs, 256, 0, stream>>>(degi, rp, bsum, N);
  k_scan2<<<1, 1024, 0, stream>>>(bsum, bsum, nbs);
  k_scan3<<<nbs, 256, 0, stream>>>(rp, bsum, N, nbs);
  if (dohist) {
    k_bscan<<<(nbuk + 3) / 4, 256, 0, stream>>>(histT, rp, offs, nbuk);
    k_place<<<NBLK, 256, 0, stream>>>(ept, E, flag, offs, ebuk, nbuk);
    k_bsort<<<nbuk, 256, 0, stream>>>(ebuk, rp, csrc, N, nbuk);
  } else {
    hipMemsetAsync(degi, 0, (size_t)N * 4, stream);
    k_scatter_fb<<<eb, 256, 0, stream>>>(ept, E, flag, rp, degi, csrc);
  }

  int n4 = N * DD / 4;
  k_cvt_x<<<1024, 256, 0, stream>>>((const float4*)x, (ushort4*)xb, n4, part);
  k_prep_w<<<128, 256, 0, stream>>>(W1, W2, wimg);

  int gb = (N + 127) / 128;
  int ab = (N + 3) / 4;
  k_gemm<<<gb, 256, 0, stream>>>(xb, wimg, dinv, h, N);
  k_agg<<<ab, 256, 0, stream>>>(h, dinv, b1, rp, csrc, y1, N, part, 128);
  k_gemm<<<gb, 256, 0, stream>>>(y1, wimg + 16384, dinv, h, N);
  k_agg<<<ab, 256, 0, stream>>>(h, dinv, b2, rp, csrc, y2, N, part, 256);

  k_fold_a<<<1, 384, 0, stream>>>(part, gamma, beta, Wo, bo, aS, boP, N);
  k_foldw<<<192, 256, 0, stream>>>(aS, Wo, wopimg);
  k_gemm_out<<<gb, 256, 0, stream>>>(xb, y1, y2, wopimg, boP, out, N);
}

// Round 6
// 385.776 us; speedup vs baseline: 2.5492x; 1.1197x over previous
//
#include <hip/hip_runtime.h>
#include <hip/hip_bf16.h>

#define DD 128
#define NBLK 256     // blocks for hist/place passes
#define MAXBUK 1024  // max dst-buckets (256 nodes each) supported by LDS path
#define CAP2 12288   // max edges per bucket for LDS sort staging

typedef __attribute__((ext_vector_type(8))) short bf16x8;
typedef __attribute__((ext_vector_type(4))) float f32x4;
typedef unsigned int uint32;

__device__ __forceinline__ unsigned short f2b(float f) {
  __hip_bfloat16 h = __float2bfloat16(f);
  unsigned short u;
  __builtin_memcpy(&u, &h, 2);
  return u;
}
__device__ __forceinline__ float b2f_lo(uint32 v) { return __uint_as_float(v << 16); }
__device__ __forceinline__ float b2f_hi(uint32 v) { return __uint_as_float(v & 0xffff0000u); }

__device__ __forceinline__ void acc8(float* acc, uint4 h, float w) {
  acc[0] = fmaf(w, b2f_lo(h.x), acc[0]);
  acc[1] = fmaf(w, b2f_hi(h.x), acc[1]);
  acc[2] = fmaf(w, b2f_lo(h.y), acc[2]);
  acc[3] = fmaf(w, b2f_hi(h.y), acc[3]);
  acc[4] = fmaf(w, b2f_lo(h.z), acc[4]);
  acc[5] = fmaf(w, b2f_hi(h.z), acc[5]);
  acc[6] = fmaf(w, b2f_lo(h.w), acc[6]);
  acc[7] = fmaf(w, b2f_hi(h.w), acc[7]);
}

// ---------------- edge dtype detect ----------------
__global__ void k_detect(const int* __restrict__ e, int pairs, int* __restrict__ flag) {
  __shared__ int nz;
  if (threadIdx.x == 0) nz = 0;
  __syncthreads();
  int samples = pairs < 4096 ? pairs : 4096;
  for (int i = threadIdx.x; i < samples; i += blockDim.x)
    if (e[2 * i + 1] != 0) atomicAdd(&nz, 1);
  __syncthreads();
  if (threadIdx.x == 0) *flag = (nz == 0) ? 1 : 0;  // 1 => underlying int64
}

// ---------------- degree count + per-block bucket histogram ----------------
__global__ __launch_bounds__(256) void k_hist(const void* __restrict__ eptr, int E,
                                              const int* __restrict__ flag,
                                              int* __restrict__ degi, int* __restrict__ histT,
                                              int nbuk, int dohist) {
  __shared__ int hist[MAXBUK];
  int t = threadIdx.x, blk = blockIdx.x;
  if (dohist)
    for (int b = t; b < nbuk; b += 256) hist[b] = 0;
  __syncthreads();
  int chunk = (E + NBLK - 1) / NBLK;
  int i0 = blk * chunk, i1 = min(E, i0 + chunk);
  bool f = (*flag) != 0;
  for (int i = i0 + t; i < i1; i += 256) {
    int dst = f ? (int)((const long long*)eptr)[E + i] : ((const int*)eptr)[E + i];
    atomicAdd(&degi[dst], 1);
    if (dohist) atomicAdd(&hist[dst >> 8], 1);
  }
  __syncthreads();
  if (dohist)
    for (int b = t; b < nbuk; b += 256) histT[b * NBLK + blk] = hist[b];
}

// ---------------- 3-phase parallel exclusive scan (rp over degi) + fused dinv ----------------
__global__ void k_scan1(const int* __restrict__ cnt, int* __restrict__ rp,
                        int* __restrict__ bsum, int n, float* __restrict__ dinv) {
  __shared__ int ws[4];
  int t = threadIdx.x, lane = t & 63, wv = t >> 6;
  int i = blockIdx.x * 256 + t;
  int v = (i < n) ? cnt[i] : 0;
  if (i < n) dinv[i] = rsqrtf((float)v + 1.0f);
  int incl = v;
#pragma unroll
  for (int o = 1; o < 64; o <<= 1) {
    int u = __shfl_up(incl, o);
    if (lane >= o) incl += u;
  }
  if (lane == 63) ws[wv] = incl;
  __syncthreads();
  int off = 0;
  for (int k = 0; k < wv; ++k) off += ws[k];
  if (i < n) rp[i] = incl - v + off;
  if (t == 255) bsum[blockIdx.x] = off + incl;
}

__global__ void k_scan2(const int* __restrict__ cnt, int* __restrict__ rp, int n) {
  __shared__ int wsum[16];
  __shared__ int ctot;
  int t = threadIdx.x, lane = t & 63, wid = t >> 6;
  int base = 0;
  for (int start = 0; start < n; start += 1024) {
    int i = start + t;
    int v = (i < n) ? cnt[i] : 0;
    int incl = v;
#pragma unroll
    for (int o = 1; o < 64; o <<= 1) {
      int u = __shfl_up(incl, o);
      if (lane >= o) incl += u;
    }
    if (lane == 63) wsum[wid] = incl;
    __syncthreads();
    if (t < 16) {
      int s = wsum[t];
      int e = s;
#pragma unroll
      for (int o = 1; o < 16; o <<= 1) {
        int u = __shfl_up(e, o, 16);
        if (t >= o) e += u;
      }
      wsum[t] = e - s;
      if (t == 15) ctot = e;
    }
    __syncthreads();
    if (i < n) rp[i] = base + wsum[wid] + incl - v;
    base += ctot;
    __syncthreads();
  }
  if (t == 0) rp[n] = base;
}

__global__ void k_scan3(int* __restrict__ rp, const int* __restrict__ bsumex, int n, int nb) {
  int i = blockIdx.x * 256 + threadIdx.x;
  if (i < n) rp[i] += bsumex[blockIdx.x];
  if (i == 0) rp[n] = bsumex[nb];
}

// ---------------- bucket scan: offs[b][blk] = global write base ----------------
__global__ void k_bscan(const int* __restrict__ histT, const int* __restrict__ rp,
                        int* __restrict__ offs, int nbuk) {
  int t = threadIdx.x, lane = t & 63, wid = t >> 6;
  int b = blockIdx.x * 4 + wid;
  if (b >= nbuk) return;
  int base = rp[b << 8];
  int idx = b * NBLK + lane * 4;
  int v0 = histT[idx], v1 = histT[idx + 1], v2 = histT[idx + 2], v3 = histT[idx + 3];
  int lsum = v0 + v1 + v2 + v3;
  int incl = lsum;
#pragma unroll
  for (int o = 1; o < 64; o <<= 1) {
    int u = __shfl_up(incl, o);
    if (lane >= o) incl += u;
  }
  int excl = base + incl - lsum;
  offs[idx] = excl;
  offs[idx + 1] = excl + v0;
  offs[idx + 2] = excl + v0 + v1;
  offs[idx + 3] = excl + v0 + v1 + v2;
}

// ---------------- place edges into bucket regions (block-contiguous runs) ----------------
__global__ __launch_bounds__(256) void k_place(const void* __restrict__ eptr, int E,
                                               const int* __restrict__ flag,
                                               const int* __restrict__ offs,
                                               int* __restrict__ ebuk, int nbuk) {
  __shared__ int cur[MAXBUK];
  int t = threadIdx.x, blk = blockIdx.x;
  for (int b = t; b < nbuk; b += 256) cur[b] = offs[b * NBLK + blk];
  __syncthreads();
  int chunk = (E + NBLK - 1) / NBLK;
  int i0 = blk * chunk, i1 = min(E, i0 + chunk);
  bool f = (*flag) != 0;
  for (int i = i0 + t; i < i1; i += 256) {
    int src, dst;
    if (f) {
      src = (int)((const long long*)eptr)[i];
      dst = (int)((const long long*)eptr)[E + i];
    } else {
      src = ((const int*)eptr)[i];
      dst = ((const int*)eptr)[E + i];
    }
    int pos = atomicAdd(&cur[dst >> 8], 1);
    ebuk[pos] = (src << 8) | (dst & 255);
  }
}

// ---------------- per-bucket LDS counting sort -> csrc ----------------
__global__ __launch_bounds__(256) void k_bsort(const int* __restrict__ ebuk,
                                               const int* __restrict__ rp,
                                               int* __restrict__ csrc, int n, int nbuk) {
  __shared__ int curs[256];
  __shared__ int outb[CAP2];
  int b = blockIdx.x, t = threadIdx.x;
  int v0 = b << 8;
  int v1 = min(v0 + 256, n);
  int base = rp[v0];
  int cnt = rp[v1] - base;
  int nn = v1 - v0;
  if (t < nn) curs[t] = rp[v0 + t] - base;
  __syncthreads();
  if (cnt <= CAP2) {
    for (int i = t; i < cnt; i += 256) {
      int e = ebuk[base + i];
      int slot = atomicAdd(&curs[e & 255], 1);
      outb[slot] = e >> 8;
    }
    __syncthreads();
    for (int i = t; i < cnt; i += 256) csrc[base + i] = outb[i];
  } else {
    for (int i = t; i < cnt; i += 256) {
      int e = ebuk[base + i];
      int slot = atomicAdd(&curs[e & 255], 1);
      csrc[base + slot] = e >> 8;
    }
  }
}

// fallback scatter (only if nbuk > MAXBUK; never for this dataset)
__global__ void k_scatter_fb(const void* __restrict__ eptr, int E, const int* __restrict__ flag,
                             const int* __restrict__ rp, int* __restrict__ cur,
                             int* __restrict__ csrc) {
  int i = blockIdx.x * 256 + threadIdx.x;
  if (i >= E) return;
  bool f = (*flag) != 0;
  int src, dst;
  if (f) {
    src = (int)((const long long*)eptr)[i];
    dst = (int)((const long long*)eptr)[E + i];
  } else {
    src = ((const int*)eptr)[i];
    dst = ((const int*)eptr)[E + i];
  }
  int pos = rp[dst] + atomicAdd(&cur[dst], 1);
  csrc[pos] = src;
}

// ---------------- x -> bf16, fused x column stats ----------------
__global__ __launch_bounds__(256) void k_cvt_x(const float4* __restrict__ x,
                                               ushort4* __restrict__ xb, int n4,
                                               float* __restrict__ part) {
  int t = threadIdx.x;
  float s[4] = {0, 0, 0, 0}, q[4] = {0, 0, 0, 0};
  for (int i = blockIdx.x * 256 + t; i < n4; i += gridDim.x * 256) {
    float4 a = x[i];
    ushort4 o;
    o.x = f2b(a.x); o.y = f2b(a.y); o.z = f2b(a.z); o.w = f2b(a.w);
    xb[i] = o;
    s[0] += a.x; s[1] += a.y; s[2] += a.z; s[3] += a.w;
    q[0] = fmaf(a.x, a.x, q[0]); q[1] = fmaf(a.y, a.y, q[1]);
    q[2] = fmaf(a.z, a.z, q[2]); q[3] = fmaf(a.w, a.w, q[3]);
  }
  __shared__ float sh[256][8];
#pragma unroll
  for (int j = 0; j < 4; ++j) { sh[t][j] = s[j]; sh[t][4 + j] = q[j]; }
  __syncthreads();
  if (t < 32) {
#pragma unroll
    for (int g = 1; g < 8; ++g)
#pragma unroll
      for (int j = 0; j < 4; ++j) {
        s[j] += sh[g * 32 + t][j];
        q[j] += sh[g * 32 + t][4 + j];
      }
    float* pp = part + (size_t)(blockIdx.x & 63) * 768;
#pragma unroll
    for (int j = 0; j < 4; ++j) {
      atomicAdd(&pp[(t * 4 + j) * 2], s[j]);
      atomicAdd(&pp[(t * 4 + j) * 2 + 1], q[j]);
    }
  }
}

// ---------------- W1/W2 -> pre-swizzled bf16 LDS image ----------------
__global__ void k_prep_w(const float* __restrict__ W1, const float* __restrict__ W2,
                         unsigned short* __restrict__ wimg) {
  int i = blockIdx.x * 256 + threadIdx.x;  // 0..32767
  if (i >= 32768) return;
  int wsel = i >> 14;
  int j = i & 16383;
  int k = j >> 7, col = j & 127;
  float v = (wsel ? W2 : W1)[j];
  int chunk = (k >> 3) ^ (col & 7);
  wimg[wsel * 16384 + col * 128 + chunk * 8 + (k & 7)] = f2b(v);
}

// ---------------- MFMA GEMM: H = bf16((A @ W) * dinv[row]) ----------------
__global__ __launch_bounds__(256) void k_gemm(const unsigned short* __restrict__ Ab,
                                              const unsigned short* __restrict__ Wimg,
                                              const float* __restrict__ dinv,
                                              unsigned short* __restrict__ H, int n) {
  __shared__ __align__(16) unsigned short Wl[16384];
  int t = threadIdx.x, lane = t & 63, w = t >> 6;
#pragma unroll
  for (int i = t; i < 2048; i += 256) ((int4*)Wl)[i] = ((const int4*)Wimg)[i];
  __syncthreads();
  int rowBase = blockIdx.x * 128 + w * 32;
  int r16 = lane & 15, half = lane >> 4;
  f32x4 acc[2][8];
#pragma unroll
  for (int m = 0; m < 2; ++m)
#pragma unroll
    for (int nn = 0; nn < 8; ++nn) acc[m][nn] = (f32x4){0.f, 0.f, 0.f, 0.f};
#pragma unroll
  for (int ks = 0; ks < 4; ++ks) {
    bf16x8 a[2];
#pragma unroll
    for (int m = 0; m < 2; ++m) {
      int r = rowBase + m * 16 + r16;
      if (r >= n) r = n - 1;
      a[m] = *(const bf16x8*)(Ab + (size_t)r * DD + ks * 32 + half * 8);
    }
#pragma unroll
    for (int nn = 0; nn < 8; ++nn) {
      int col = nn * 16 + r16;
      int chunk = (ks * 4 + half) ^ (col & 7);
      bf16x8 b = *(const bf16x8*)(Wl + col * 128 + chunk * 8);
      acc[0][nn] = __builtin_amdgcn_mfma_f32_16x16x32_bf16(a[0], b, acc[0][nn], 0, 0, 0);
      acc[1][nn] = __builtin_amdgcn_mfma_f32_16x16x32_bf16(a[1], b, acc[1][nn], 0, 0, 0);
    }
  }
#pragma unroll
  for (int m = 0; m < 2; ++m) {
    int rb = rowBase + m * 16 + half * 4;
    float dv[4];
#pragma unroll
    for (int i = 0; i < 4; ++i) dv[i] = (rb + i < n) ? dinv[rb + i] : 0.f;
#pragma unroll
    for (int nn = 0; nn < 8; ++nn) {
      int col = nn * 16 + r16;
#pragma unroll
      for (int i = 0; i < 4; ++i) {
        int r = rb + i;
        if (r < n) H[(size_t)r * DD + col] = f2b(acc[m][nn][i] * dv[i]);
      }
    }
  }
}

// ---------------- aggregation: 2 nodes/wave, 8 gather loads in flight + fused stats ----------------
__global__ __launch_bounds__(256) void k_agg(const unsigned short* __restrict__ hs,
                                             const float* __restrict__ dinv,
                                             const float* __restrict__ b,
                                             const int* __restrict__ rp,
                                             const int* __restrict__ csrc,
                                             unsigned short* __restrict__ y, int n,
                                             float* __restrict__ part, int cb) {
  __shared__ float sh_s[8][128];
  __shared__ float sh_q[8][128];
  int wid = threadIdx.x >> 6, lane = threadIdx.x & 63;
  int eidx = lane >> 4;  // 0..3: edge group
  int seg = lane & 15;   // 0..15: 16B segment of the row
  int vA = blockIdx.x * 8 + wid;
  int vB = vA + 4;
  bool okA = vA < n, okB = vB < n;
  int a0 = 0, b0 = 0, a1 = 0, b1 = 0;
  if (okA) { a0 = rp[vA]; b0 = rp[vA + 1]; }
  if (okB) { a1 = rp[vB]; b1 = rp[vB + 1]; }
  const uint4* H4 = (const uint4*)hs;  // one row = 16 uint4
  uint4 selfA = okA ? H4[(size_t)vA * 16 + seg] : make_uint4(0, 0, 0, 0);
  uint4 selfB = okB ? H4[(size_t)vB * 16 + seg] : make_uint4(0, 0, 0, 0);
  float accA[8], accB[8];
#pragma unroll
  for (int j = 0; j < 8; ++j) { accA[j] = 0.f; accB[j] = 0.f; }
  int ebA = a0, ebB = a1;
  while (ebA < b0 || ebB < b1) {
    int ecA = b0 - ebA; ecA = ecA < 0 ? 0 : (ecA > 64 ? 64 : ecA);
    int ecB = b1 - ebB; ecB = ecB < 0 ? 0 : (ecB > 64 ? 64 : ecB);
    int ulA = (ebA + lane < b0) ? csrc[ebA + lane] : 0;
    int ulB = (ebB + lane < b1) ? csrc[ebB + lane] : 0;
    int iters = ecA > ecB ? ecA : ecB;
    for (int cc = 0; cc < iters; cc += 16) {
      int uA0 = __shfl(ulA, cc + eidx), uA1 = __shfl(ulA, cc + 4 + eidx);
      int uA2 = __shfl(ulA, cc + 8 + eidx), uA3 = __shfl(ulA, cc + 12 + eidx);
      int uB0 = __shfl(ulB, cc + eidx), uB1 = __shfl(ulB, cc + 4 + eidx);
      int uB2 = __shfl(ulB, cc + 8 + eidx), uB3 = __shfl(ulB, cc + 12 + eidx);
      float wA0 = (cc + eidx < ecA) ? 1.f : 0.f;
      float wA1 = (cc + 4 + eidx < ecA) ? 1.f : 0.f;
      float wA2 = (cc + 8 + eidx < ecA) ? 1.f : 0.f;
      float wA3 = (cc + 12 + eidx < ecA) ? 1.f : 0.f;
      float wB0 = (cc + eidx < ecB) ? 1.f : 0.f;
      float wB1 = (cc + 4 + eidx < ecB) ? 1.f : 0.f;
      float wB2 = (cc + 8 + eidx < ecB) ? 1.f : 0.f;
      float wB3 = (cc + 12 + eidx < ecB) ? 1.f : 0.f;
      uint4 hA0 = H4[(size_t)uA0 * 16 + seg];
      uint4 hA1 = H4[(size_t)uA1 * 16 + seg];
      uint4 hA2 = H4[(size_t)uA2 * 16 + seg];
      uint4 hA3 = H4[(size_t)uA3 * 16 + seg];
      uint4 hB0 = H4[(size_t)uB0 * 16 + seg];
      uint4 hB1 = H4[(size_t)uB1 * 16 + seg];
      uint4 hB2 = H4[(size_t)uB2 * 16 + seg];
      uint4 hB3 = H4[(size_t)uB3 * 16 + seg];
      acc8(accA, hA0, wA0); acc8(accA, hA1, wA1);
      acc8(accA, hA2, wA2); acc8(accA, hA3, wA3);
      acc8(accB, hB0, wB0); acc8(accB, hB1, wB1);
      acc8(accB, hB2, wB2); acc8(accB, hB3, wB3);
    }
    ebA += 64;
    ebB += 64;
  }
  // butterfly-reduce across the 4 edge-groups (lanes differing in bits 4,5)
#pragma unroll
  for (int j = 0; j < 8; ++j) {
    accA[j] += __shfl_xor(accA[j], 16);
    accA[j] += __shfl_xor(accA[j], 32);
    accB[j] += __shfl_xor(accB[j], 16);
    accB[j] += __shfl_xor(accB[j], 32);
  }
  float4 bb0 = ((const float4*)b)[seg * 2];
  float4 bb1 = ((const float4*)b)[seg * 2 + 1];
  float bv[8] = {bb0.x, bb0.y, bb0.z, bb0.w, bb1.x, bb1.y, bb1.z, bb1.w};
  float oA[8], oB[8];
  if (okA) {
    float sf[8] = {b2f_lo(selfA.x), b2f_hi(selfA.x), b2f_lo(selfA.y), b2f_hi(selfA.y),
                   b2f_lo(selfA.z), b2f_hi(selfA.z), b2f_lo(selfA.w), b2f_hi(selfA.w)};
    float dv = dinv[vA];
#pragma unroll
    for (int j = 0; j < 8; ++j) oA[j] = fmaxf(fmaf(dv, accA[j] + sf[j], bv[j]), 0.f);
    if (eidx == 0) {
      uint4 ov;
      ov.x = (uint32)f2b(oA[0]) | ((uint32)f2b(oA[1]) << 16);
      ov.y = (uint32)f2b(oA[2]) | ((uint32)f2b(oA[3]) << 16);
      ov.z = (uint32)f2b(oA[4]) | ((uint32)f2b(oA[5]) << 16);
      ov.w = (uint32)f2b(oA[6]) | ((uint32)f2b(oA[7]) << 16);
      ((uint4*)y)[(size_t)vA * 16 + seg] = ov;
    }
  } else {
#pragma unroll
    for (int j = 0; j < 8; ++j) oA[j] = 0.f;
  }
  if (okB) {
    float sf[8] = {b2f_lo(selfB.x), b2f_hi(selfB.x), b2f_lo(selfB.y), b2f_hi(selfB.y),
                   b2f_lo(selfB.z), b2f_hi(selfB.z), b2f_lo(selfB.w), b2f_hi(selfB.w)};
    float dv = dinv[vB];
#pragma unroll
    for (int j = 0; j < 8; ++j) oB[j] = fmaxf(fmaf(dv, accB[j] + sf[j], bv[j]), 0.f);
    if (eidx == 0) {
      uint4 ov;
      ov.x = (uint32)f2b(oB[0]) | ((uint32)f2b(oB[1]) << 16);
      ov.y = (uint32)f2b(oB[2]) | ((uint32)f2b(oB[3]) << 16);
      ov.z = (uint32)f2b(oB[4]) | ((uint32)f2b(oB[5]) << 16);
      ov.w = (uint32)f2b(oB[6]) | ((uint32)f2b(oB[7]) << 16);
      ((uint4*)y)[(size_t)vB * 16 + seg] = ov;
    }
  } else {
#pragma unroll
    for (int j = 0; j < 8; ++j) oB[j] = 0.f;
  }
  if (eidx == 0) {
#pragma unroll
    for (int j = 0; j < 8; ++j) {
      sh_s[wid][seg * 8 + j] = oA[j];
      sh_q[wid][seg * 8 + j] = oA[j] * oA[j];
      sh_s[wid + 4][seg * 8 + j] = oB[j];
      sh_q[wid + 4][seg * 8 + j] = oB[j] * oB[j];
    }
  }
  __syncthreads();
  if (threadIdx.x < 128) {
    int c = threadIdx.x;
    float s = 0.f, q = 0.f;
#pragma unroll
    for (int k2 = 0; k2 < 8; ++k2) {
      s += sh_s[k2][c];
      q += sh_q[k2][c];
    }
    float* pp = part + (size_t)(blockIdx.x & 63) * 768;
    atomicAdd(&pp[(cb + c) * 2], s);
    atomicAdd(&pp[(cb + c) * 2 + 1], q);
  }
}

// ---------------- BN fold: reduce partials, compute scale/shift + folded bias ----------------
__global__ void k_fold_a(const float* __restrict__ part, const float* __restrict__ gamma,
                         const float* __restrict__ beta, const float* __restrict__ Wo,
                         const float* __restrict__ bo, float* __restrict__ aS,
                         float* __restrict__ boP, int n) {
  __shared__ float cSh[384];
  int t = threadIdx.x;  // 0..383
  float s = 0.f, q = 0.f;
  for (int r = 0; r < 64; ++r) {
    s += part[r * 768 + t * 2];
    q += part[r * 768 + t * 2 + 1];
  }
  float inv_n = 1.0f / (float)n;
  float mu = s * inv_n;
  float var = q * inv_n - mu * mu;
  float a = gamma[t] * rsqrtf(var + 1e-5f);
  aS[t] = a;
  cSh[t] = beta[t] - mu * a;
  __syncthreads();
  if (t < DD) {
    float sb = bo[t];
    for (int k = 0; k < 384; ++k) sb = fmaf(cSh[k], Wo[k * DD + t], sb);
    boP[t] = sb;
  }
}

// ---------------- WoP image (bf16, pre-swizzled) ----------------
__global__ void k_foldw(const float* __restrict__ aS, const float* __restrict__ Wo,
                        unsigned short* __restrict__ wopimg) {
  int i = blockIdx.x * 256 + threadIdx.x;  // 0..49151
  if (i >= 49152) return;
  int krow = i >> 7, col = i & 127;
  float v = aS[krow] * Wo[i];
  int p = krow >> 7, kk = krow & 127;
  int chunk = (kk >> 3) ^ (col & 7);
  wopimg[p * 16384 + col * 128 + chunk * 8 + (kk & 7)] = f2b(v);
}

// ---------------- final MFMA GEMM: out = [xb|y1|y2] @ WoP + boP (f32 out) ----------------
__global__ __launch_bounds__(256) void k_gemm_out(const unsigned short* __restrict__ xb,
                                                  const unsigned short* __restrict__ y1,
                                                  const unsigned short* __restrict__ y2,
                                                  const unsigned short* __restrict__ Wimg3,
                                                  const float* __restrict__ boP,
                                                  float* __restrict__ out, int n) {
  __shared__ __align__(16) unsigned short Wl[16384];
  int t = threadIdx.x, lane = t & 63, w = t >> 6;
  int rowBase = blockIdx.x * 128 + w * 32;
  int r16 = lane & 15, half = lane >> 4;
  f32x4 acc[2][8];
#pragma unroll
  for (int m = 0; m < 2; ++m)
#pragma unroll
    for (int nn = 0; nn < 8; ++nn) acc[m][nn] = (f32x4){0.f, 0.f, 0.f, 0.f};
  for (int p = 0; p < 3; ++p) {
    const unsigned short* Ab = (p == 0) ? xb : (p == 1) ? y1 : y2;
    __syncthreads();
#pragma unroll
    for (int i = t; i < 2048; i += 256) ((int4*)Wl)[i] = ((const int4*)(Wimg3 + p * 16384))[i];
    __syncthreads();
#pragma unroll
    for (int ks = 0; ks < 4; ++ks) {
      bf16x8 a[2];
#pragma unroll
      for (int m = 0; m < 2; ++m) {
        int r = rowBase + m * 16 + r16;
        if (r >= n) r = n - 1;
        a[m] = *(const bf16x8*)(Ab + (size_t)r * DD + ks * 32 + half * 8);
      }
#pragma unroll
      for (int nn = 0; nn < 8; ++nn) {
        int col = nn * 16 + r16;
        int chunk = (ks * 4 + half) ^ (col & 7);
        bf16x8 b = *(const bf16x8*)(Wl + col * 128 + chunk * 8);
        acc[0][nn] = __builtin_amdgcn_mfma_f32_16x16x32_bf16(a[0], b, acc[0][nn], 0, 0, 0);
        acc[1][nn] = __builtin_amdgcn_mfma_f32_16x16x32_bf16(a[1], b, acc[1][nn], 0, 0, 0);
      }
    }
  }
#pragma unroll
  for (int m = 0; m < 2; ++m) {
    int rb = rowBase + m * 16 + half * 4;
#pragma unroll
    for (int nn = 0; nn < 8; ++nn) {
      int col = nn * 16 + r16;
      float bb = boP[col];
#pragma unroll
      for (int i = 0; i < 4; ++i) {
        int r = rb + i;
        if (r < n) out[(size_t)r * DD + col] = acc[m][nn][i] + bb;
      }
    }
  }
}

extern "C" void kernel_launch(void* const* d_in, const int* in_sizes, int n_in,
                              void* d_out, int out_size, void* d_ws, size_t ws_size,
                              hipStream_t stream) {
  const float* x = (const float*)d_in[0];
  const void* ept = d_in[1];
  const float* W1 = (const float*)d_in[2];
  const float* b1 = (const float*)d_in[3];
  const float* W2 = (const float*)d_in[4];
  const float* b2 = (const float*)d_in[5];
  const float* gamma = (const float*)d_in[6];
  const float* beta = (const float*)d_in[7];
  const float* Wo = (const float*)d_in[8];
  const float* bo = (const float*)d_in[9];
  float* out = (float*)d_out;
  int N = in_sizes[0] / DD;
  int E = in_sizes[1] / 2;
  int nbuk = (N + 255) >> 8;

  char* w = (char*)d_ws;
  size_t off = 0;
  auto alloc = [&](size_t bytes) {
    void* p = w + off;
    off = (off + bytes + 255) & ~(size_t)255;
    return p;
  };
  float* dinv = (float*)alloc((size_t)N * 4);
  int* degi = (int*)alloc((size_t)N * 4);
  int* rp = (int*)alloc((size_t)(N + 1) * 4);
  int* csrc = (int*)alloc((size_t)E * 4);
  int* ebuk = (int*)alloc((size_t)E * 4);
  int* histT = (int*)alloc((size_t)MAXBUK * NBLK * 4);
  int* offs = (int*)alloc((size_t)MAXBUK * NBLK * 4);
  unsigned short* xb = (unsigned short*)alloc((size_t)N * DD * 2);
  unsigned short* h = (unsigned short*)alloc((size_t)N * DD * 2);
  unsigned short* y1 = (unsigned short*)alloc((size_t)N * DD * 2);
  unsigned short* y2 = (unsigned short*)alloc((size_t)N * DD * 2);
  unsigned short* wimg = (unsigned short*)alloc(32768 * 2);
  unsigned short* wopimg = (unsigned short*)alloc(49152 * 2);
  float* part = (float*)alloc((size_t)64 * 768 * 4);
  float* aS = (float*)alloc(384 * 4);
  float* boP = (float*)alloc(DD * 4);
  int* flag = (int*)alloc(4);
  int nbs = (N + 255) / 256;
  int* bsum = (int*)alloc((size_t)(nbs + 1) * 4);

  int dohist = (nbuk <= MAXBUK) ? 1 : 0;

  hipMemsetAsync(degi, 0, (size_t)N * 4, stream);
  hipMemsetAsync(part, 0, (size_t)64 * 768 * 4, stream);

  int eb = (E + 255) / 256;
  k_detect<<<1, 256, 0, stream>>>((const int*)ept, E, flag);
  k_hist<<<NBLK, 256, 0, stream>>>(ept, E, flag, degi, histT, nbuk, dohist);
  k_scan1<<<nbs, 256, 0, stream>>>(degi, rp, bsum, N, dinv);
  k_scan2<<<1, 1024, 0, stream>>>(bsum, bsum, nbs);
  k_scan3<<<nbs, 256, 0, stream>>>(rp, bsum, N, nbs);
  if (dohist) {
    k_bscan<<<(nbuk + 3) / 4, 256, 0, stream>>>(histT, rp, offs, nbuk);
    k_place<<<NBLK, 256, 0, stream>>>(ept, E, flag, offs, ebuk, nbuk);
    k_bsort<<<nbuk, 256, 0, stream>>>(ebuk, rp, csrc, N, nbuk);
  } else {
    hipMemsetAsync(degi, 0, (size_t)N * 4, stream);
    k_scatter_fb<<<eb, 256, 0, stream>>>(ept, E, flag, rp, degi, csrc);
  }

  int n4 = N * DD / 4;
  k_cvt_x<<<1024, 256, 0, stream>>>((const float4*)x, (ushort4*)xb, n4, part);
  k_prep_w<<<128, 256, 0, stream>>>(W1, W2, wimg);

  int gb = (N + 127) / 128;
  int ab = (N + 7) / 8;
  k_gemm<<<gb, 256, 0, stream>>>(xb, wimg, dinv, h, N);
  k_agg<<<ab, 256, 0, stream>>>(h, dinv, b1, rp, csrc, y1, N, part, 128);
  k_gemm<<<gb, 256, 0, stream>>>(y1, wimg + 16384, dinv, h, N);
  k_agg<<<ab, 256, 0, stream>>>(h, dinv, b2, rp, csrc, y2, N, part, 256);

  k_fold_a<<<1, 384, 0, stream>>>(part, gamma, beta, Wo, bo, aS, boP, N);
  k_foldw<<<192, 256, 0, stream>>>(aS, Wo, wopimg);
  k_gemm_out<<<gb, 256, 0, stream>>>(xb, y1, y2, wopimg, boP, out, N);
}

// Round 7
// 340.089 us; speedup vs baseline: 2.8916x; 1.1343x over previous
//
#include <hip/hip_runtime.h>
#include <hip/hip_bf16.h>

#define DD 128
#define NBLK 256     // blocks for hist/place passes
#define MAXBUK 1024  // max dst-buckets (256 nodes each)
#define CAP2 12288   // max edges per bucket for LDS sort staging

typedef __attribute__((ext_vector_type(8))) short bf16x8;
typedef __attribute__((ext_vector_type(4))) float f32x4;
typedef unsigned int uint32;

__device__ __forceinline__ unsigned short f2b(float f) {
  __hip_bfloat16 h = __float2bfloat16(f);
  unsigned short u;
  __builtin_memcpy(&u, &h, 2);
  return u;
}
__device__ __forceinline__ float b2f_lo(uint32 v) { return __uint_as_float(v << 16); }
__device__ __forceinline__ float b2f_hi(uint32 v) { return __uint_as_float(v & 0xffff0000u); }

__device__ __forceinline__ void acc8(float* acc, uint4 h, float w) {
  acc[0] = fmaf(w, b2f_lo(h.x), acc[0]);
  acc[1] = fmaf(w, b2f_hi(h.x), acc[1]);
  acc[2] = fmaf(w, b2f_lo(h.y), acc[2]);
  acc[3] = fmaf(w, b2f_hi(h.y), acc[3]);
  acc[4] = fmaf(w, b2f_lo(h.z), acc[4]);
  acc[5] = fmaf(w, b2f_hi(h.z), acc[5]);
  acc[6] = fmaf(w, b2f_lo(h.w), acc[6]);
  acc[7] = fmaf(w, b2f_hi(h.w), acc[7]);
}

// per-block int64-vs-int32 detection: hi-words of first 64 src entries all zero <=> int64
__device__ __forceinline__ bool detect_i64(const int* e, int E) {
  int lane = threadIdx.x & 63;
  int samples = E < 64 ? E : 64;
  int v = (lane < samples) ? e[2 * lane + 1] : 0;
  return __ballot(v != 0) == 0ULL;
}

// ---------------- per-block bucket histogram ----------------
__global__ __launch_bounds__(256) void k_hist(const void* __restrict__ eptr, int E,
                                              int* __restrict__ histT, int nbuk) {
  __shared__ int hist[MAXBUK];
  int t = threadIdx.x, blk = blockIdx.x;
  bool f = detect_i64((const int*)eptr, E);
  for (int b = t; b < nbuk; b += 256) hist[b] = 0;
  __syncthreads();
  int chunk = (E + NBLK - 1) / NBLK;
  int i0 = blk * chunk, i1 = min(E, i0 + chunk);
  for (int i = i0 + t; i < i1; i += 256) {
    int dst = f ? (int)((const long long*)eptr)[E + i] : ((const int*)eptr)[E + i];
    atomicAdd(&hist[dst >> 8], 1);
  }
  __syncthreads();
  for (int b = t; b < nbuk; b += 256) histT[b * NBLK + blk] = hist[b];
}

// ---------------- single-block: bucket totals, bucket base scan, per-block offsets ----------------
__global__ __launch_bounds__(1024) void k_bktscan(const int* __restrict__ histT,
                                                  int* __restrict__ offs,
                                                  int* __restrict__ bucketBase,
                                                  int nbuk, int E) {
  __shared__ int tot[MAXBUK];
  int t = threadIdx.x, lane = t & 63, wv = t >> 6;  // 16 waves
  for (int b = t; b < MAXBUK; b += 1024) tot[b] = 0;
  __syncthreads();
  // phase A: per-bucket totals (wave per bucket; 4 hist values per lane)
  for (int b = wv; b < nbuk; b += 16) {
    const int4 vv = *(const int4*)(histT + b * NBLK + lane * 4);
    int lsum = vv.x + vv.y + vv.z + vv.w;
    int s = lsum;
#pragma unroll
    for (int o = 1; o < 64; o <<= 1) {
      int u = __shfl_up(s, o);
      if (lane >= o) s += u;
    }
    if (lane == 63) tot[b] = s;
  }
  __syncthreads();
  // phase B: in-place inclusive Hillis-Steele scan of tot[0..MAXBUK) (1024 threads)
  for (int o = 1; o < MAXBUK; o <<= 1) {
    int u = (t >= o) ? tot[t - o] : 0;
    __syncthreads();
    tot[t] += u;
    __syncthreads();
  }
  // phase C: offsets
  for (int b = wv; b < nbuk; b += 16) {
    int idx = b * NBLK + lane * 4;
    const int4 vv = *(const int4*)(histT + idx);
    int lsum = vv.x + vv.y + vv.z + vv.w;
    int s = lsum;
#pragma unroll
    for (int o = 1; o < 64; o <<= 1) {
      int u = __shfl_up(s, o);
      if (lane >= o) s += u;
    }
    int tb = __shfl(s, 63);            // bucket total
    int bbase = tot[b] - tb;           // exclusive bucket base
    int excl = bbase + s - lsum;
    offs[idx] = excl;
    offs[idx + 1] = excl + vv.x;
    offs[idx + 2] = excl + vv.x + vv.y;
    offs[idx + 3] = excl + vv.x + vv.y + vv.z;
    if (lane == 0) bucketBase[b] = bbase;
  }
  if (t == 0) bucketBase[nbuk] = E;
}

// ---------------- place edges into bucket regions (block-contiguous runs) ----------------
__global__ __launch_bounds__(256) void k_place(const void* __restrict__ eptr, int E,
                                               const int* __restrict__ offs,
                                               int* __restrict__ ebuk, int nbuk) {
  __shared__ int cur[MAXBUK];
  int t = threadIdx.x, blk = blockIdx.x;
  bool f = detect_i64((const int*)eptr, E);
  for (int b = t; b < nbuk; b += 256) cur[b] = offs[b * NBLK + blk];
  __syncthreads();
  int chunk = (E + NBLK - 1) / NBLK;
  int i0 = blk * chunk, i1 = min(E, i0 + chunk);
  for (int i = i0 + t; i < i1; i += 256) {
    int src, dst;
    if (f) {
      src = (int)((const long long*)eptr)[i];
      dst = (int)((const long long*)eptr)[E + i];
    } else {
      src = ((const int*)eptr)[i];
      dst = ((const int*)eptr)[E + i];
    }
    int pos = atomicAdd(&cur[dst >> 8], 1);
    ebuk[pos] = (src << 8) | (dst & 255);
  }
}

// ---------------- per-bucket: degree count -> rp + dinv + LDS counting sort -> csrc ----------------
__global__ __launch_bounds__(256) void k_bsort2(const int* __restrict__ ebuk,
                                                const int* __restrict__ bucketBase,
                                                int* __restrict__ rp, float* __restrict__ dinv,
                                                int* __restrict__ csrc, int n) {
  __shared__ int cnt[256];
  __shared__ int wss[4];
  __shared__ int outb[CAP2];
  int b = blockIdx.x, t = threadIdx.x, lane = t & 63, wv = t >> 6;
  int v0 = b << 8;
  int v1 = min(v0 + 256, n);
  int nn = v1 - v0;
  int base = bucketBase[b];
  int total = bucketBase[b + 1] - base;
  cnt[t] = 0;
  __syncthreads();
  for (int i = t; i < total; i += 256) atomicAdd(&cnt[ebuk[base + i] & 255], 1);
  __syncthreads();
  int v = cnt[t];
  // block exclusive scan over cnt[256]
  int incl = v;
#pragma unroll
  for (int o = 1; o < 64; o <<= 1) {
    int u = __shfl_up(incl, o);
    if (lane >= o) incl += u;
  }
  if (lane == 63) wss[wv] = incl;
  __syncthreads();
  int woff = 0;
  for (int k = 0; k < wv; ++k) woff += wss[k];
  int excl = woff + incl - v;
  if (t < nn) {
    rp[v0 + t] = base + excl;
    dinv[v0 + t] = rsqrtf((float)v + 1.0f);
  }
  if (t == 255) rp[v1] = base + excl + v;  // == base + total
  __syncthreads();
  cnt[t] = excl;  // reuse as cursors
  __syncthreads();
  if (total <= CAP2) {
    for (int i = t; i < total; i += 256) {
      int e = ebuk[base + i];
      int slot = atomicAdd(&cnt[e & 255], 1);
      outb[slot] = e >> 8;
    }
    __syncthreads();
    for (int i = t; i < total; i += 256) csrc[base + i] = outb[i];
  } else {
    for (int i = t; i < total; i += 256) {
      int e = ebuk[base + i];
      int slot = atomicAdd(&cnt[e & 255], 1);
      csrc[base + slot] = e >> 8;
    }
  }
}

// ---------------- fused: x -> bf16 + column stats (blocks 0..1023), W prep (1024..1151) ----------------
__global__ __launch_bounds__(256) void k_cvtw(const float4* __restrict__ x,
                                              ushort4* __restrict__ xb, int n4,
                                              float* __restrict__ part,
                                              const float* __restrict__ W1,
                                              const float* __restrict__ W2,
                                              unsigned short* __restrict__ wimg) {
  __shared__ float sh[256][8];
  int t = threadIdx.x;
  int bid = blockIdx.x;
  if (bid >= 1024) {
    int i = (bid - 1024) * 256 + t;  // 0..32767
    if (i < 32768) {
      int wsel = i >> 14;
      int j = i & 16383;
      int k = j >> 7, col = j & 127;
      float v = (wsel ? W2 : W1)[j];
      int chunk = (k >> 3) ^ (col & 7);
      wimg[wsel * 16384 + col * 128 + chunk * 8 + (k & 7)] = f2b(v);
    }
    return;
  }
  float s[4] = {0, 0, 0, 0}, q[4] = {0, 0, 0, 0};
  for (int i = bid * 256 + t; i < n4; i += 1024 * 256) {
    float4 a = x[i];
    ushort4 o;
    o.x = f2b(a.x); o.y = f2b(a.y); o.z = f2b(a.z); o.w = f2b(a.w);
    xb[i] = o;
    s[0] += a.x; s[1] += a.y; s[2] += a.z; s[3] += a.w;
    q[0] = fmaf(a.x, a.x, q[0]); q[1] = fmaf(a.y, a.y, q[1]);
    q[2] = fmaf(a.z, a.z, q[2]); q[3] = fmaf(a.w, a.w, q[3]);
  }
#pragma unroll
  for (int j = 0; j < 4; ++j) { sh[t][j] = s[j]; sh[t][4 + j] = q[j]; }
  __syncthreads();
  if (t < 32) {
#pragma unroll
    for (int g = 1; g < 8; ++g)
#pragma unroll
      for (int j = 0; j < 4; ++j) {
        s[j] += sh[g * 32 + t][j];
        q[j] += sh[g * 32 + t][4 + j];
      }
    float* pp = part + (size_t)(bid & 63) * 768;
#pragma unroll
    for (int j = 0; j < 4; ++j) {
      atomicAdd(&pp[(t * 4 + j) * 2], s[j]);
      atomicAdd(&pp[(t * 4 + j) * 2 + 1], q[j]);
    }
  }
}

// ---------------- MFMA GEMM: H = bf16((A @ W) * dinv[row]) ----------------
__global__ __launch_bounds__(256) void k_gemm(const unsigned short* __restrict__ Ab,
                                              const unsigned short* __restrict__ Wimg,
                                              const float* __restrict__ dinv,
                                              unsigned short* __restrict__ H, int n) {
  __shared__ __align__(16) unsigned short Wl[16384];
  int t = threadIdx.x, lane = t & 63, w = t >> 6;
#pragma unroll
  for (int i = t; i < 2048; i += 256) ((int4*)Wl)[i] = ((const int4*)Wimg)[i];
  __syncthreads();
  int rowBase = blockIdx.x * 128 + w * 32;
  int r16 = lane & 15, half = lane >> 4;
  f32x4 acc[2][8];
#pragma unroll
  for (int m = 0; m < 2; ++m)
#pragma unroll
    for (int nn = 0; nn < 8; ++nn) acc[m][nn] = (f32x4){0.f, 0.f, 0.f, 0.f};
#pragma unroll
  for (int ks = 0; ks < 4; ++ks) {
    bf16x8 a[2];
#pragma unroll
    for (int m = 0; m < 2; ++m) {
      int r = rowBase + m * 16 + r16;
      if (r >= n) r = n - 1;
      a[m] = *(const bf16x8*)(Ab + (size_t)r * DD + ks * 32 + half * 8);
    }
#pragma unroll
    for (int nn = 0; nn < 8; ++nn) {
      int col = nn * 16 + r16;
      int chunk = (ks * 4 + half) ^ (col & 7);
      bf16x8 b = *(const bf16x8*)(Wl + col * 128 + chunk * 8);
      acc[0][nn] = __builtin_amdgcn_mfma_f32_16x16x32_bf16(a[0], b, acc[0][nn], 0, 0, 0);
      acc[1][nn] = __builtin_amdgcn_mfma_f32_16x16x32_bf16(a[1], b, acc[1][nn], 0, 0, 0);
    }
  }
#pragma unroll
  for (int m = 0; m < 2; ++m) {
    int rb = rowBase + m * 16 + half * 4;
    float dv[4];
#pragma unroll
    for (int i = 0; i < 4; ++i) dv[i] = (rb + i < n) ? dinv[rb + i] : 0.f;
#pragma unroll
    for (int nn = 0; nn < 8; ++nn) {
      int col = nn * 16 + r16;
#pragma unroll
      for (int i = 0; i < 4; ++i) {
        int r = rb + i;
        if (r < n) H[(size_t)r * DD + col] = f2b(acc[m][nn][i] * dv[i]);
      }
    }
  }
}

// ---------------- aggregation: 2 nodes/wave, 8 gather loads in flight + fused stats ----------------
__global__ __launch_bounds__(256) void k_agg(const unsigned short* __restrict__ hs,
                                             const float* __restrict__ dinv,
                                             const float* __restrict__ b,
                                             const int* __restrict__ rp,
                                             const int* __restrict__ csrc,
                                             unsigned short* __restrict__ y, int n,
                                             float* __restrict__ part, int cb) {
  __shared__ float sh_s[8][128];
  __shared__ float sh_q[8][128];
  int wid = threadIdx.x >> 6, lane = threadIdx.x & 63;
  int eidx = lane >> 4;  // 0..3: edge group
  int seg = lane & 15;   // 0..15: 16B segment of the row
  int vA = blockIdx.x * 8 + wid;
  int vB = vA + 4;
  bool okA = vA < n, okB = vB < n;
  int a0 = 0, b0 = 0, a1 = 0, b1 = 0;
  if (okA) { a0 = rp[vA]; b0 = rp[vA + 1]; }
  if (okB) { a1 = rp[vB]; b1 = rp[vB + 1]; }
  const uint4* H4 = (const uint4*)hs;  // one row = 16 uint4
  uint4 selfA = okA ? H4[(size_t)vA * 16 + seg] : make_uint4(0, 0, 0, 0);
  uint4 selfB = okB ? H4[(size_t)vB * 16 + seg] : make_uint4(0, 0, 0, 0);
  float accA[8], accB[8];
#pragma unroll
  for (int j = 0; j < 8; ++j) { accA[j] = 0.f; accB[j] = 0.f; }
  int ebA = a0, ebB = a1;
  while (ebA < b0 || ebB < b1) {
    int ecA = b0 - ebA; ecA = ecA < 0 ? 0 : (ecA > 64 ? 64 : ecA);
    int ecB = b1 - ebB; ecB = ecB < 0 ? 0 : (ecB > 64 ? 64 : ecB);
    int ulA = (ebA + lane < b0) ? csrc[ebA + lane] : 0;
    int ulB = (ebB + lane < b1) ? csrc[ebB + lane] : 0;
    int iters = ecA > ecB ? ecA : ecB;
    for (int cc = 0; cc < iters; cc += 16) {
      int uA0 = __shfl(ulA, cc + eidx), uA1 = __shfl(ulA, cc + 4 + eidx);
      int uA2 = __shfl(ulA, cc + 8 + eidx), uA3 = __shfl(ulA, cc + 12 + eidx);
      int uB0 = __shfl(ulB, cc + eidx), uB1 = __shfl(ulB, cc + 4 + eidx);
      int uB2 = __shfl(ulB, cc + 8 + eidx), uB3 = __shfl(ulB, cc + 12 + eidx);
      float wA0 = (cc + eidx < ecA) ? 1.f : 0.f;
      float wA1 = (cc + 4 + eidx < ecA) ? 1.f : 0.f;
      float wA2 = (cc + 8 + eidx < ecA) ? 1.f : 0.f;
      float wA3 = (cc + 12 + eidx < ecA) ? 1.f : 0.f;
      float wB0 = (cc + eidx < ecB) ? 1.f : 0.f;
      float wB1 = (cc + 4 + eidx < ecB) ? 1.f : 0.f;
      float wB2 = (cc + 8 + eidx < ecB) ? 1.f : 0.f;
      float wB3 = (cc + 12 + eidx < ecB) ? 1.f : 0.f;
      uint4 hA0 = H4[(size_t)uA0 * 16 + seg];
      uint4 hA1 = H4[(size_t)uA1 * 16 + seg];
      uint4 hA2 = H4[(size_t)uA2 * 16 + seg];
      uint4 hA3 = H4[(size_t)uA3 * 16 + seg];
      uint4 hB0 = H4[(size_t)uB0 * 16 + seg];
      uint4 hB1 = H4[(size_t)uB1 * 16 + seg];
      uint4 hB2 = H4[(size_t)uB2 * 16 + seg];
      uint4 hB3 = H4[(size_t)uB3 * 16 + seg];
      acc8(accA, hA0, wA0); acc8(accA, hA1, wA1);
      acc8(accA, hA2, wA2); acc8(accA, hA3, wA3);
      acc8(accB, hB0, wB0); acc8(accB, hB1, wB1);
      acc8(accB, hB2, wB2); acc8(accB, hB3, wB3);
    }
    ebA += 64;
    ebB += 64;
  }
#pragma unroll
  for (int j = 0; j < 8; ++j) {
    accA[j] += __shfl_xor(accA[j], 16);
    accA[j] += __shfl_xor(accA[j], 32);
    accB[j] += __shfl_xor(accB[j], 16);
    accB[j] += __shfl_xor(accB[j], 32);
  }
  float4 bb0 = ((const float4*)b)[seg * 2];
  float4 bb1 = ((const float4*)b)[seg * 2 + 1];
  float bv[8] = {bb0.x, bb0.y, bb0.z, bb0.w, bb1.x, bb1.y, bb1.z, bb1.w};
  float oA[8], oB[8];
  if (okA) {
    float sf[8] = {b2f_lo(selfA.x), b2f_hi(selfA.x), b2f_lo(selfA.y), b2f_hi(selfA.y),
                   b2f_lo(selfA.z), b2f_hi(selfA.z), b2f_lo(selfA.w), b2f_hi(selfA.w)};
    float dv = dinv[vA];
#pragma unroll
    for (int j = 0; j < 8; ++j) oA[j] = fmaxf(fmaf(dv, accA[j] + sf[j], bv[j]), 0.f);
    if (eidx == 0) {
      uint4 ov;
      ov.x = (uint32)f2b(oA[0]) | ((uint32)f2b(oA[1]) << 16);
      ov.y = (uint32)f2b(oA[2]) | ((uint32)f2b(oA[3]) << 16);
      ov.z = (uint32)f2b(oA[4]) | ((uint32)f2b(oA[5]) << 16);
      ov.w = (uint32)f2b(oA[6]) | ((uint32)f2b(oA[7]) << 16);
      ((uint4*)y)[(size_t)vA * 16 + seg] = ov;
    }
  } else {
#pragma unroll
    for (int j = 0; j < 8; ++j) oA[j] = 0.f;
  }
  if (okB) {
    float sf[8] = {b2f_lo(selfB.x), b2f_hi(selfB.x), b2f_lo(selfB.y), b2f_hi(selfB.y),
                   b2f_lo(selfB.z), b2f_hi(selfB.z), b2f_lo(selfB.w), b2f_hi(selfB.w)};
    float dv = dinv[vB];
#pragma unroll
    for (int j = 0; j < 8; ++j) oB[j] = fmaxf(fmaf(dv, accB[j] + sf[j], bv[j]), 0.f);
    if (eidx == 0) {
      uint4 ov;
      ov.x = (uint32)f2b(oB[0]) | ((uint32)f2b(oB[1]) << 16);
      ov.y = (uint32)f2b(oB[2]) | ((uint32)f2b(oB[3]) << 16);
      ov.z = (uint32)f2b(oB[4]) | ((uint32)f2b(oB[5]) << 16);
      ov.w = (uint32)f2b(oB[6]) | ((uint32)f2b(oB[7]) << 16);
      ((uint4*)y)[(size_t)vB * 16 + seg] = ov;
    }
  } else {
#pragma unroll
    for (int j = 0; j < 8; ++j) oB[j] = 0.f;
  }
  if (eidx == 0) {
#pragma unroll
    for (int j = 0; j < 8; ++j) {
      sh_s[wid][seg * 8 + j] = oA[j];
      sh_q[wid][seg * 8 + j] = oA[j] * oA[j];
      sh_s[wid + 4][seg * 8 + j] = oB[j];
      sh_q[wid + 4][seg * 8 + j] = oB[j] * oB[j];
    }
  }
  __syncthreads();
  if (threadIdx.x < 128) {
    int c = threadIdx.x;
    float s = 0.f, q = 0.f;
#pragma unroll
    for (int k2 = 0; k2 < 8; ++k2) {
      s += sh_s[k2][c];
      q += sh_q[k2][c];
    }
    float* pp = part + (size_t)(blockIdx.x & 63) * 768;
    atomicAdd(&pp[(cb + c) * 2], s);
    atomicAdd(&pp[(cb + c) * 2 + 1], q);
  }
}

// ---------------- BN fold: reduce partials, compute scale/shift + folded bias ----------------
__global__ void k_fold_a(const float* __restrict__ part, const float* __restrict__ gamma,
                         const float* __restrict__ beta, const float* __restrict__ Wo,
                         const float* __restrict__ bo, float* __restrict__ aS,
                         float* __restrict__ boP, int n) {
  __shared__ float cSh[384];
  int t = threadIdx.x;  // 0..383
  float s = 0.f, q = 0.f;
  for (int r = 0; r < 64; ++r) {
    s += part[r * 768 + t * 2];
    q += part[r * 768 + t * 2 + 1];
  }
  float inv_n = 1.0f / (float)n;
  float mu = s * inv_n;
  float var = q * inv_n - mu * mu;
  float a = gamma[t] * rsqrtf(var + 1e-5f);
  aS[t] = a;
  cSh[t] = beta[t] - mu * a;
  __syncthreads();
  if (t < DD) {
    float sb = bo[t];
    for (int k = 0; k < 384; ++k) sb = fmaf(cSh[k], Wo[k * DD + t], sb);
    boP[t] = sb;
  }
}

// ---------------- WoP image (bf16, pre-swizzled) ----------------
__global__ void k_foldw(const float* __restrict__ aS, const float* __restrict__ Wo,
                        unsigned short* __restrict__ wopimg) {
  int i = blockIdx.x * 256 + threadIdx.x;  // 0..49151
  if (i >= 49152) return;
  int krow = i >> 7, col = i & 127;
  float v = aS[krow] * Wo[i];
  int p = krow >> 7, kk = krow & 127;
  int chunk = (kk >> 3) ^ (col & 7);
  wopimg[p * 16384 + col * 128 + chunk * 8 + (kk & 7)] = f2b(v);
}

// ---------------- final MFMA GEMM: out = [xb|y1|y2] @ WoP + boP (f32 out) ----------------
__global__ __launch_bounds__(256) void k_gemm_out(const unsigned short* __restrict__ xb,
                                                  const unsigned short* __restrict__ y1,
                                                  const unsigned short* __restrict__ y2,
                                                  const unsigned short* __restrict__ Wimg3,
                                                  const float* __restrict__ boP,
                                                  float* __restrict__ out, int n) {
  __shared__ __align__(16) unsigned short Wl[16384];
  int t = threadIdx.x, lane = t & 63, w = t >> 6;
  int rowBase = blockIdx.x * 128 + w * 32;
  int r16 = lane & 15, half = lane >> 4;
  f32x4 acc[2][8];
#pragma unroll
  for (int m = 0; m < 2; ++m)
#pragma unroll
    for (int nn = 0; nn < 8; ++nn) acc[m][nn] = (f32x4){0.f, 0.f, 0.f, 0.f};
  for (int p = 0; p < 3; ++p) {
    const unsigned short* Ab = (p == 0) ? xb : (p == 1) ? y1 : y2;
    __syncthreads();
#pragma unroll
    for (int i = t; i < 2048; i += 256) ((int4*)Wl)[i] = ((const int4*)(Wimg3 + p * 16384))[i];
    __syncthreads();
#pragma unroll
    for (int ks = 0; ks < 4; ++ks) {
      bf16x8 a[2];
#pragma unroll
      for (int m = 0; m < 2; ++m) {
        int r = rowBase + m * 16 + r16;
        if (r >= n) r = n - 1;
        a[m] = *(const bf16x8*)(Ab + (size_t)r * DD + ks * 32 + half * 8);
      }
#pragma unroll
      for (int nn = 0; nn < 8; ++nn) {
        int col = nn * 16 + r16;
        int chunk = (ks * 4 + half) ^ (col & 7);
        bf16x8 b = *(const bf16x8*)(Wl + col * 128 + chunk * 8);
        acc[0][nn] = __builtin_amdgcn_mfma_f32_16x16x32_bf16(a[0], b, acc[0][nn], 0, 0, 0);
        acc[1][nn] = __builtin_amdgcn_mfma_f32_16x16x32_bf16(a[1], b, acc[1][nn], 0, 0, 0);
      }
    }
  }
#pragma unroll
  for (int m = 0; m < 2; ++m) {
    int rb = rowBase + m * 16 + half * 4;
#pragma unroll
    for (int nn = 0; nn < 8; ++nn) {
      int col = nn * 16 + r16;
      float bb = boP[col];
#pragma unroll
      for (int i = 0; i < 4; ++i) {
        int r = rb + i;
        if (r < n) out[(size_t)r * DD + col] = acc[m][nn][i] + bb;
      }
    }
  }
}

extern "C" void kernel_launch(void* const* d_in, const int* in_sizes, int n_in,
                              void* d_out, int out_size, void* d_ws, size_t ws_size,
                              hipStream_t stream) {
  const float* x = (const float*)d_in[0];
  const void* ept = d_in[1];
  const float* W1 = (const float*)d_in[2];
  const float* b1 = (const float*)d_in[3];
  const float* W2 = (const float*)d_in[4];
  const float* b2 = (const float*)d_in[5];
  const float* gamma = (const float*)d_in[6];
  const float* beta = (const float*)d_in[7];
  const float* Wo = (const float*)d_in[8];
  const float* bo = (const float*)d_in[9];
  float* out = (float*)d_out;
  int N = in_sizes[0] / DD;
  int E = in_sizes[1] / 2;
  int nbuk = (N + 255) >> 8;  // must be <= MAXBUK (N <= 262144)

  char* w = (char*)d_ws;
  size_t off = 0;
  auto alloc = [&](size_t bytes) {
    void* p = w + off;
    off = (off + bytes + 255) & ~(size_t)255;
    return p;
  };
  float* dinv = (float*)alloc((size_t)N * 4);
  int* rp = (int*)alloc((size_t)(N + 1) * 4);
  int* csrc = (int*)alloc((size_t)E * 4);
  int* ebuk = (int*)alloc((size_t)E * 4);
  int* histT = (int*)alloc((size_t)MAXBUK * NBLK * 4);
  int* offs = (int*)alloc((size_t)MAXBUK * NBLK * 4);
  int* bucketBase = (int*)alloc((size_t)(MAXBUK + 1) * 4);
  unsigned short* xb = (unsigned short*)alloc((size_t)N * DD * 2);
  unsigned short* h = (unsigned short*)alloc((size_t)N * DD * 2);
  unsigned short* y1 = (unsigned short*)alloc((size_t)N * DD * 2);
  unsigned short* y2 = (unsigned short*)alloc((size_t)N * DD * 2);
  unsigned short* wimg = (unsigned short*)alloc(32768 * 2);
  unsigned short* wopimg = (unsigned short*)alloc(49152 * 2);
  float* part = (float*)alloc((size_t)64 * 768 * 4);
  float* aS = (float*)alloc(384 * 4);
  float* boP = (float*)alloc(DD * 4);

  hipMemsetAsync(part, 0, (size_t)64 * 768 * 4, stream);

  // CSR construction (atomic-free, bucketized)
  k_hist<<<NBLK, 256, 0, stream>>>(ept, E, histT, nbuk);
  k_bktscan<<<1, 1024, 0, stream>>>(histT, offs, bucketBase, nbuk, E);
  k_place<<<NBLK, 256, 0, stream>>>(ept, E, offs, ebuk, nbuk);
  k_bsort2<<<nbuk, 256, 0, stream>>>(ebuk, bucketBase, rp, dinv, csrc, N);

  // x conversion + stats, W prep (fused)
  int n4 = N * DD / 4;
  k_cvtw<<<1024 + 128, 256, 0, stream>>>((const float4*)x, (ushort4*)xb, n4, part, W1, W2, wimg);

  int gb = (N + 127) / 128;
  int ab = (N + 7) / 8;
  k_gemm<<<gb, 256, 0, stream>>>(xb, wimg, dinv, h, N);
  k_agg<<<ab, 256, 0, stream>>>(h, dinv, b1, rp, csrc, y1, N, part, 128);
  k_gemm<<<gb, 256, 0, stream>>>(y1, wimg + 16384, dinv, h, N);
  k_agg<<<ab, 256, 0, stream>>>(h, dinv, b2, rp, csrc, y2, N, part, 256);

  k_fold_a<<<1, 384, 0, stream>>>(part, gamma, beta, Wo, bo, aS, boP, N);
  k_foldw<<<192, 256, 0, stream>>>(aS, Wo, wopimg);
  k_gemm_out<<<gb, 256, 0, stream>>>(xb, y1, y2, wopimg, boP, out, N);
}